// Round 9
// baseline (591.752 us; speedup 1.0000x reference)
//
#include <hip/hip_runtime.h>
#include <hip/hip_bf16.h>
#include <math.h>

#define B_ 2
#define N_ 2048
#define D_ 512
#define E_ 1024
#define S_ 16
#define R_ 32
#define C_ 512
#define CH_ 32
#define NC_ (N_ / CH_)   // 64 chunks
#define GRID_ 512

using short8 = __attribute__((ext_vector_type(8))) short;
using f32x4  = __attribute__((ext_vector_type(4))) float;
using f32x16 = __attribute__((ext_vector_type(16))) float;

__device__ __forceinline__ short f2bf(float f) {
    union { float f; unsigned u; } x; x.f = f;
    unsigned r = (x.u + 0x7fffu + ((x.u >> 16) & 1u)) >> 16;
    return (short)r;
}
__device__ __forceinline__ float bf2f(short s) {
    union { unsigned u; float f; } x;
    x.u = ((unsigned)(unsigned short)s) << 16;
    return x.f;
}

// device-scope grid barrier: all GRID_ blocks co-resident (guaranteed by
// __launch_bounds__(256,2) + 37.4KB LDS -> >=2 blocks/CU on 256 CUs).
// counter is monotonic; target = GRID_ * phase; reset by hipMemsetAsync per launch.
__device__ __forceinline__ void gbar(unsigned* cnt, unsigned target) {
    __syncthreads();
    if (threadIdx.x == 0) {
        __threadfence();   // device-scope release (L2 writeback for cross-XCD)
        __hip_atomic_fetch_add(cnt, 1u, __ATOMIC_ACQ_REL, __HIP_MEMORY_SCOPE_AGENT);
        while (__hip_atomic_load(cnt, __ATOMIC_ACQUIRE, __HIP_MEMORY_SCOPE_AGENT) < target)
            __builtin_amdgcn_s_sleep(8);
    }
    __syncthreads();
}

__global__ __launch_bounds__(256, 2) void fused_all(
    const float* __restrict__ x, const float* __restrict__ cond,
    const float* __restrict__ ln_g, const float* __restrict__ ln_b,
    const float* __restrict__ W_in, const float* __restrict__ conv_w,
    const float* __restrict__ conv_b, const float* __restrict__ W_x,
    const float* __restrict__ W_dt, const float* __restrict__ b_dt,
    const float* __restrict__ A_log, const float* __restrict__ D_skip,
    const float* __restrict__ W_out, const float* __restrict__ film_gw,
    const float* __restrict__ film_gb, const float* __restrict__ film_bw,
    const float* __restrict__ film_bb, float* __restrict__ out,
    float* __restrict__ ws) {
    // ---- workspace layout (mirrors host) ----
    float* xdbl   = ws;
    float* gamma  = xdbl + 262144;
    float* beta   = gamma + 1024;
    float2* stats = (float2*)(beta + 1024);
    float* hend   = (float*)(stats + 4096);
    float* cumd   = hend + 2097152;
    short* xzb    = (short*)(cumd + 131072);
    short* ucb    = xzb + 8388608;
    short* deltab = ucb + 4194304;
    short* Wint   = deltab + 4194304;
    short* Woutt  = Wint + 1048576;
    short* yb     = Woutt + 524288;
    short* Wxt    = yb + 4194304;
    short* Wdtt   = Wxt + 65536;
    unsigned* cnt = (unsigned*)(Wdtt + 32768);

    __shared__ __align__(16) char smem[37376];
    int bid = blockIdx.x;
    int tid = threadIdx.x;
    int lane = tid & 63, w = tid >> 6;

    // ================= P0: prep (film | transposes | ln_stats), units striped =================
    for (int uu = bid; uu < 5736; uu += GRID_) {
        __syncthreads();
        if (uu < 8) {
            float* cs  = (float*)smem;          // [2][512]
            float* red = (float*)smem + 1024;   // [4][64][4]
            int d0 = uu * 64;
#pragma unroll
            for (int i = tid; i < 2 * C_ / 4; i += 256) {
                int b = i >> 7;
                int c4 = (i & 127) * 4;
                *(float4*)&cs[b * C_ + c4] = *(const float4*)(cond + (size_t)b * C_ + c4);
            }
            __syncthreads();
            int dl = tid & 63, ks = tid >> 6;
            int d = d0 + dl;
            float g0 = 0.f, g1 = 0.f, bt0 = 0.f, bt1 = 0.f;
#pragma unroll 4
            for (int k = ks * 128; k < ks * 128 + 128; k++) {
                float wg = film_gw[(size_t)k * D_ + d];
                float wb = film_bw[(size_t)k * D_ + d];
                float c0 = cs[k], c1 = cs[C_ + k];
                g0 = fmaf(c0, wg, g0);
                g1 = fmaf(c1, wg, g1);
                bt0 = fmaf(c0, wb, bt0);
                bt1 = fmaf(c1, wb, bt1);
            }
            red[(ks * 64 + dl) * 4 + 0] = g0; red[(ks * 64 + dl) * 4 + 1] = g1;
            red[(ks * 64 + dl) * 4 + 2] = bt0; red[(ks * 64 + dl) * 4 + 3] = bt1;
            __syncthreads();
            if (ks == 0) {
                float s0 = 0.f, s1 = 0.f, s2 = 0.f, s3 = 0.f;
#pragma unroll
                for (int q = 0; q < 4; q++) {
                    s0 += red[(q * 64 + dl) * 4 + 0]; s1 += red[(q * 64 + dl) * 4 + 1];
                    s2 += red[(q * 64 + dl) * 4 + 2]; s3 += red[(q * 64 + dl) * 4 + 3];
                }
                float gbv = film_gb[d], bbv = film_bb[d];
                gamma[d] = s0 + gbv;
                gamma[D_ + d] = s1 + gbv;
                beta[d] = s2 + bbv;
                beta[D_ + d] = s3 + bbv;
            }
        } else if (uu < 1640) {
            const float* W; short* Wt; int K, N, bx, by;
            int r = uu - 8;
            if (r < 1024)      { W = W_in;  Wt = Wint;  K = 512;  N = 2048; bx = r % 64; by = r / 64; }
            else if (r < 1536) { r -= 1024; W = W_out; Wt = Woutt; K = 1024; N = 512; bx = r % 16; by = r / 16; }
            else if (r < 1600) { r -= 1536; W = W_x;   Wt = Wxt;   K = 1024; N = 64;  bx = r % 2;  by = r / 2; }
            else               { r -= 1600; W = W_dt;  Wt = Wdtt;  K = 32;   N = 1024; bx = r;     by = 0; }
            float (*t)[33] = (float(*)[33])smem;
            int n0 = bx * 32, k0 = by * 32;
            int c = tid & 31, rr0 = tid >> 5;
#pragma unroll
            for (int rr = rr0; rr < 32; rr += 8)
                t[rr][c] = W[(size_t)(k0 + rr) * N + n0 + c];
            __syncthreads();
#pragma unroll
            for (int rr = rr0; rr < 32; rr += 8)
                Wt[(size_t)(n0 + rr) * K + k0 + c] = f2bf(t[c][rr]);
        } else {
            int t = uu - 1640;
            float* red = (float*)smem;
            float2 v = *(const float2*)(x + (size_t)t * D_ + tid * 2);
            float s = v.x + v.y;
            float s2 = fmaf(v.x, v.x, v.y * v.y);
#pragma unroll
            for (int o = 32; o >= 1; o >>= 1) {
                s += __shfl_down(s, o);
                s2 += __shfl_down(s2, o);
            }
            int wid = tid >> 6;
            if ((tid & 63) == 0) { red[wid] = s; red[4 + wid] = s2; }
            __syncthreads();
            if (tid == 0) {
                float sum = red[0] + red[1] + red[2] + red[3];
                float sum2 = red[4] + red[5] + red[6] + red[7];
                float mu = sum * (1.f / (float)D_);
                float var = sum2 * (1.f / (float)D_) - mu * mu;
                stats[t] = make_float2(mu, rsqrtf(var + 1e-5f));
            }
        }
    }
    gbar(cnt, GRID_ * 1);

    // ================= P1: xz = LN(x) @ W_in -> bf16, 128x128 tiles, XCD-swizzled =================
    {
        short* As = (short*)smem;        // [128][72]
        short* Bs = As + 128 * 72;
        int xcd = bid & 7, i5 = bid >> 3;
        int by = xcd * 4 + (i5 >> 4);    // m-tile 0..31
        int bx = i5 & 15;                // n-tile 0..15
        int m0 = by * 128, n0 = bx * 128;
        int wr = w >> 1, wc = w & 1;
        int l31 = lane & 31, hk = (lane >> 5) * 8;
        f32x16 acc[2][2];
#pragma unroll
        for (int i = 0; i < 2; i++)
#pragma unroll
            for (int j = 0; j < 2; j++)
#pragma unroll
                for (int r = 0; r < 16; r++) acc[i][j][r] = 0.f;
        for (int k0 = 0; k0 < 512; k0 += 64) {
            __syncthreads();
#pragma unroll
            for (int i = tid; i < 128 * 8; i += 256) {
                int r = i >> 3, c = (i & 7) * 8;
                float2 st = stats[m0 + r];
                const float* src = x + (size_t)(m0 + r) * 512 + k0 + c;
                float4 v0 = *(const float4*)src;
                float4 v1 = *(const float4*)(src + 4);
                float4 g0 = *(const float4*)(ln_g + k0 + c);
                float4 g1 = *(const float4*)(ln_g + k0 + c + 4);
                float4 b0 = *(const float4*)(ln_b + k0 + c);
                float4 b1 = *(const float4*)(ln_b + k0 + c + 4);
                short8 o;
                o[0] = f2bf((v0.x - st.x) * st.y * g0.x + b0.x);
                o[1] = f2bf((v0.y - st.x) * st.y * g0.y + b0.y);
                o[2] = f2bf((v0.z - st.x) * st.y * g0.z + b0.z);
                o[3] = f2bf((v0.w - st.x) * st.y * g0.w + b0.w);
                o[4] = f2bf((v1.x - st.x) * st.y * g1.x + b1.x);
                o[5] = f2bf((v1.y - st.x) * st.y * g1.y + b1.y);
                o[6] = f2bf((v1.z - st.x) * st.y * g1.z + b1.z);
                o[7] = f2bf((v1.w - st.x) * st.y * g1.w + b1.w);
                *(short8*)&As[r * 72 + c] = o;
            }
#pragma unroll
            for (int i = tid; i < 128 * 8; i += 256) {
                int r = i >> 3, c = (i & 7) * 8;
                *(short8*)&Bs[r * 72 + c] = *(const short8*)&Wint[(size_t)(n0 + r) * 512 + k0 + c];
            }
            __syncthreads();
#pragma unroll
            for (int kk = 0; kk < 4; kk++) {
                short8 a[2], b[2];
#pragma unroll
                for (int i = 0; i < 2; i++)
                    a[i] = *(const short8*)&As[(wr * 64 + i * 32 + l31) * 72 + kk * 16 + hk];
#pragma unroll
                for (int j = 0; j < 2; j++)
                    b[j] = *(const short8*)&Bs[(wc * 64 + j * 32 + l31) * 72 + kk * 16 + hk];
#pragma unroll
                for (int i = 0; i < 2; i++)
#pragma unroll
                    for (int j = 0; j < 2; j++)
                        acc[i][j] = __builtin_amdgcn_mfma_f32_32x32x16_bf16(a[i], b[j], acc[i][j], 0, 0, 0);
            }
        }
        int rbase = 4 * (lane >> 5);
#pragma unroll
        for (int i = 0; i < 2; i++)
#pragma unroll
            for (int j = 0; j < 2; j++) {
                int col = n0 + wc * 64 + j * 32 + l31;
#pragma unroll
                for (int r = 0; r < 16; r++) {
                    int row = m0 + wr * 64 + i * 32 + rbase + (r & 3) + 8 * (r >> 2);
                    xzb[(size_t)row * 2048 + col] = f2bf(acc[i][j][r]);
                }
            }
    }
    gbar(cnt, GRID_ * 2);

    // ================= P2: mid (conv+SiLU -> xproj -> dt), 8 tokens/block =================
    {
        constexpr int LDU = 1032;
        short* u = (short*)smem;                 // [16][1032] (rows 0..10 filled)
        float* xd = (float*)(smem + 33024);      // [16][68]
        int t0 = bid * 8;
        int n0 = t0 & (N_ - 1);
        for (int i = tid; i < 11 * 128; i += 256) {
            int r = i >> 7, c8 = (i & 127) * 8;
            short8 v = {0, 0, 0, 0, 0, 0, 0, 0};
            if (n0 + r - 3 >= 0)
                v = *(const short8*)&xzb[(size_t)(t0 + r - 3) * (2 * E_) + c8];
            *(short8*)&u[r * LDU + c8] = v;
        }
        __syncthreads();
#pragma unroll
        for (int q = 0; q < 4; q++) {
            int e = tid + q * 256;
            float4 cwv = *(const float4*)(conv_w + e * 4);
            float cbv = conv_b[e];
            float u0 = bf2f(u[0 * LDU + e]);
            float u1 = bf2f(u[1 * LDU + e]);
            float u2 = bf2f(u[2 * LDU + e]);
#pragma unroll
            for (int n = 0; n < 8; n++) {
                float u3 = bf2f(u[(n + 3) * LDU + e]);
                float a = fmaf(cwv.x, u0, fmaf(cwv.y, u1, fmaf(cwv.z, u2, fmaf(cwv.w, u3, cbv))));
                float v = a / (1.f + __expf(-a));
                short vb = f2bf(v);
                ucb[(size_t)(t0 + n) * E_ + e] = vb;
                u[n * LDU + e] = vb;
                u0 = u1; u1 = u2; u2 = u3;
            }
        }
        __syncthreads();
        int l15 = lane & 15, kq = (lane >> 4) * 8;
        // xproj: wave w -> cols [w*16, w*16+16), full K=1024 (rows 8..15 discarded)
        f32x4 acc4 = {0.f, 0.f, 0.f, 0.f};
#pragma unroll 8
        for (int k0 = 0; k0 < 32; k0++) {
            short8 af = *(const short8*)&u[l15 * LDU + k0 * 32 + kq];
            short8 bfr = *(const short8*)&Wxt[(size_t)(w * 16 + l15) * E_ + k0 * 32 + kq];
            acc4 = __builtin_amdgcn_mfma_f32_16x16x32_bf16(af, bfr, acc4, 0, 0, 0);
        }
#pragma unroll
        for (int j = 0; j < 4; j++)
            xd[((lane >> 4) * 4 + j) * 68 + w * 16 + l15] = acc4[j];
        __syncthreads();
        if (tid < 128) {
            int r = tid >> 4, c4 = (tid & 15) * 4;
            *(float4*)&xdbl[(size_t)(t0 + r) * 64 + c4] = *(const float4*)&xd[r * 68 + c4];
        }
        // dt: 4 waves x 16 e-tiles; valid output rows 0..7
        float av[8];
        *(float4*)&av[0] = *(const float4*)&xd[l15 * 68 + kq];
        *(float4*)&av[4] = *(const float4*)&xd[l15 * 68 + kq + 4];
        short8 ab;
#pragma unroll
        for (int j = 0; j < 8; j++) ab[j] = f2bf(av[j]);
        int row4 = (lane >> 4) * 4;
#pragma unroll 4
        for (int t = 0; t < 16; t++) {
            int e = w * 256 + t * 16 + l15;
            short8 bb = *(const short8*)&Wdtt[(size_t)e * 32 + kq];
            f32x4 c4v = {0.f, 0.f, 0.f, 0.f};
            c4v = __builtin_amdgcn_mfma_f32_16x16x32_bf16(ab, bb, c4v, 0, 0, 0);
            if (row4 < 8) {
                float bv = b_dt[e];
#pragma unroll
                for (int j = 0; j < 4; j++) {
                    float xv = c4v[j] + bv;
                    float sp = (xv > 20.f) ? xv : log1pf(__expf(xv));
                    deltab[(size_t)(t0 + row4 + j) * E_ + e] = f2bf(sp);
                }
            }
        }
    }
    gbar(cnt, GRID_ * 3);

    // ================= P3: scan phase1 =================
    {
        int eq = bid & 3;
        int c = (bid >> 2) & (NC_ - 1);
        int b = bid >> 8;
        int e = eq * 256 + tid;
        float* Bsl = (float*)smem;   // [32][16]
        int base = (b * N_ + c * CH_) * 64;
        for (int i = tid; i < CH_ * 16; i += 256) {
            int n = i >> 4, col = i & 15;
            Bsl[n * 16 + col] = xdbl[base + n * 64 + R_ + col];
        }
        float Aes[16];
        const float4* al = (const float4*)(A_log + e * 16);
#pragma unroll
        for (int j = 0; j < 4; j++) {
            float4 a = al[j];
            Aes[j * 4 + 0] = -__expf(a.x);
            Aes[j * 4 + 1] = -__expf(a.y);
            Aes[j * 4 + 2] = -__expf(a.z);
            Aes[j * 4 + 3] = -__expf(a.w);
        }
        __syncthreads();
        float h[16];
#pragma unroll
        for (int s = 0; s < 16; s++) h[s] = 0.f;
        float cum = 0.f;
        const short* dp = deltab + (size_t)(b * N_ + c * CH_) * E_ + e;
        const short* up = ucb + (size_t)(b * N_ + c * CH_) * E_ + e;
#pragma unroll 2
        for (int n = 0; n < CH_; n++) {
            float dv = bf2f(dp[n * E_]);
            float uv = bf2f(up[n * E_]);
            float du = dv * uv;
            cum += dv;
            float Bl[16];
#pragma unroll
            for (int j = 0; j < 4; j++) *(float4*)&Bl[j * 4] = *(const float4*)&Bsl[n * 16 + j * 4];
#pragma unroll
            for (int s = 0; s < 16; s++) {
                float dA = __expf(dv * Aes[s]);
                h[s] = fmaf(dA, h[s], du * Bl[s]);
            }
        }
        size_t ob = (size_t)(b * NC_ + c) * 16 * E_ + e;
#pragma unroll
        for (int s = 0; s < 16; s++) hend[ob + (size_t)s * E_] = h[s];
        cumd[(size_t)(b * NC_ + c) * E_ + e] = cum;
    }
    gbar(cnt, GRID_ * 4);

    // ================= P4: combine (128 blocks active) =================
    if (bid < 128) {
        int idx = bid * 256 + tid;     // over B*S*E = 32768
        int b = idx >> 14;
        int s = (idx >> 10) & 15;
        int e = idx & 1023;
        float Aes = -__expf(A_log[e * 16 + s]);
        float h = 0.f;
#pragma unroll 4
        for (int c = 0; c < NC_; c++) {
            size_t i = ((size_t)((b * NC_ + c) * 16) + s) * E_ + e;
            float he = hend[i];
            float P = __expf(Aes * cumd[(size_t)(b * NC_ + c) * E_ + e]);
            hend[i] = h;
            h = fmaf(P, h, he);
        }
    }
    gbar(cnt, GRID_ * 5);

    // ================= P5: scan phase3 -> gated y (bf16) =================
    {
        int eq = bid & 3;
        int c = (bid >> 2) & (NC_ - 1);
        int b = bid >> 8;
        int e = eq * 256 + tid;
        float* Bsl = (float*)smem;           // [32][16]
        float* Csl = Bsl + CH_ * 16;         // [32][16]
        int base = (b * N_ + c * CH_) * 64;
        for (int i = tid; i < CH_ * 32; i += 256) {
            int n = i >> 5, col = i & 31;
            float v = xdbl[base + n * 64 + R_ + col];
            if (col < 16) Bsl[n * 16 + col] = v;
            else Csl[n * 16 + col - 16] = v;
        }
        float Aes[16];
        const float4* al = (const float4*)(A_log + e * 16);
#pragma unroll
        for (int j = 0; j < 4; j++) {
            float4 a = al[j];
            Aes[j * 4 + 0] = -__expf(a.x);
            Aes[j * 4 + 1] = -__expf(a.y);
            Aes[j * 4 + 2] = -__expf(a.z);
            Aes[j * 4 + 3] = -__expf(a.w);
        }
        float dsk = D_skip[e];
        float h[16];
        size_t ob = (size_t)(b * NC_ + c) * 16 * E_ + e;
#pragma unroll
        for (int s = 0; s < 16; s++) h[s] = hend[ob + (size_t)s * E_];
        __syncthreads();
        const short* dp = deltab + (size_t)(b * N_ + c * CH_) * E_ + e;
        const short* up = ucb + (size_t)(b * N_ + c * CH_) * E_ + e;
        const short* zp = xzb + (size_t)(b * N_ + c * CH_) * (2 * E_) + E_ + e;
        short* yp = yb + (size_t)(b * N_ + c * CH_) * E_ + e;
#pragma unroll 2
        for (int n = 0; n < CH_; n++) {
            float dv = bf2f(dp[n * E_]);
            float uv = bf2f(up[n * E_]);
            float du = dv * uv;
            float Bl[16], Cl[16];
#pragma unroll
            for (int j = 0; j < 4; j++) {
                *(float4*)&Bl[j * 4] = *(const float4*)&Bsl[n * 16 + j * 4];
                *(float4*)&Cl[j * 4] = *(const float4*)&Csl[n * 16 + j * 4];
            }
            float y = 0.f;
#pragma unroll
            for (int s = 0; s < 16; s++) {
                float dA = __expf(dv * Aes[s]);
                h[s] = fmaf(dA, h[s], du * Bl[s]);
                y = fmaf(h[s], Cl[s], y);
            }
            float zv = bf2f(zp[n * 2 * E_]);
            float yy = y + dsk * uv;
            yy = yy * (zv / (1.f + __expf(-zv)));
            yp[n * E_] = f2bf(yy);
        }
    }
    gbar(cnt, GRID_ * 6);

    // ================= P6: out = FiLM(y @ W_out), 64x64 tiles, XCD-swizzled =================
    {
        short* As = (short*)smem;        // [64][72]
        short* Bs = As + 64 * 72;
        int xcd = bid & 7, i5 = bid >> 3;
        int by = xcd * 8 + (i5 >> 3);    // m-tile 0..63
        int bx = i5 & 7;                 // n-tile 0..7
        int m0 = by * 64, n0 = bx * 64;
        int wr = w >> 1, wc = w & 1;
        int l31 = lane & 31, hk = (lane >> 5) * 8;
        f32x16 acc;
#pragma unroll
        for (int r = 0; r < 16; r++) acc[r] = 0.f;
        for (int k0 = 0; k0 < 1024; k0 += 64) {
            __syncthreads();
#pragma unroll
            for (int i = tid; i < 64 * 8; i += 256) {
                int r = i >> 3, c = (i & 7) * 8;
                *(short8*)&As[r * 72 + c] = *(const short8*)&yb[(size_t)(m0 + r) * 1024 + k0 + c];
                *(short8*)&Bs[r * 72 + c] = *(const short8*)&Woutt[(size_t)(n0 + r) * 1024 + k0 + c];
            }
            __syncthreads();
#pragma unroll
            for (int kk = 0; kk < 4; kk++) {
                short8 a = *(const short8*)&As[(wr * 32 + l31) * 72 + kk * 16 + hk];
                short8 b = *(const short8*)&Bs[(wc * 32 + l31) * 72 + kk * 16 + hk];
                acc = __builtin_amdgcn_mfma_f32_32x32x16_bf16(a, b, acc, 0, 0, 0);
            }
        }
        int rbase = 4 * (lane >> 5);
        int bi = m0 >> 11;
        int col = n0 + wc * 32 + l31;
        float gm = gamma[bi * D_ + col];
        float bt = beta[bi * D_ + col];
#pragma unroll
        for (int r = 0; r < 16; r++) {
            int row = m0 + wr * 32 + rbase + (r & 3) + 8 * (r >> 2);
            out[(size_t)row * D_ + col] = gm * acc[r] + bt;
        }
    }
}

extern "C" void kernel_launch(void* const* d_in, const int* in_sizes, int n_in,
                              void* d_out, int out_size, void* d_ws, size_t ws_size,
                              hipStream_t stream) {
    const float* x       = (const float*)d_in[0];
    const float* cond    = (const float*)d_in[1];
    const float* ln_g    = (const float*)d_in[2];
    const float* ln_b    = (const float*)d_in[3];
    const float* W_in    = (const float*)d_in[4];
    const float* conv_w  = (const float*)d_in[5];
    const float* conv_b  = (const float*)d_in[6];
    const float* W_x     = (const float*)d_in[7];
    const float* W_dt    = (const float*)d_in[8];
    const float* b_dt    = (const float*)d_in[9];
    const float* A_log   = (const float*)d_in[10];
    const float* D_skip  = (const float*)d_in[11];
    const float* W_out   = (const float*)d_in[12];
    const float* film_gw = (const float*)d_in[13];
    const float* film_gb = (const float*)d_in[14];
    const float* film_bw = (const float*)d_in[15];
    const float* film_bb = (const float*)d_in[16];
    float* out = (float*)d_out;
    float* ws = (float*)d_ws;

    // barrier counter lives at Wdtt + 32768 (see in-kernel layout); zero it each launch
    float* xdbl_h   = ws;
    float* cumd_end = xdbl_h + 262144 + 1024 + 1024 + 8192 + 2097152 + 131072;
    short* xzb_h    = (short*)cumd_end;
    unsigned* cnt   = (unsigned*)(xzb_h + 8388608 + 4194304 + 4194304 + 1048576 + 524288 + 4194304 + 65536 + 32768);
    hipMemsetAsync(cnt, 0, 64, stream);

    fused_all<<<GRID_, 256, 0, stream>>>(
        x, cond, ln_g, ln_b, W_in, conv_w, conv_b, W_x, W_dt, b_dt,
        A_log, D_skip, W_out, film_gw, film_gb, film_bw, film_bb, out, ws);
}

// Round 10
// 167.912 us; speedup vs baseline: 3.5242x; 3.5242x over previous
//
#include <hip/hip_runtime.h>
#include <hip/hip_bf16.h>
#include <math.h>

#define B_ 2
#define N_ 2048
#define D_ 512
#define E_ 1024
#define S_ 16
#define R_ 32
#define C_ 512
#define CH_ 32
#define NC_ (N_ / CH_)   // 64 chunks

using short8 = __attribute__((ext_vector_type(8))) short;
using f32x4  = __attribute__((ext_vector_type(4))) float;
using f32x16 = __attribute__((ext_vector_type(16))) float;

__device__ __forceinline__ short f2bf(float f) {
    union { float f; unsigned u; } x; x.f = f;
    unsigned r = (x.u + 0x7fffu + ((x.u >> 16) & 1u)) >> 16;
    return (short)r;
}
__device__ __forceinline__ float bf2f(short s) {
    union { unsigned u; float f; } x;
    x.u = ((unsigned)(unsigned short)s) << 16;
    return x.f;
}
// wave-level async global->LDS, 16B per lane (lds dest wave-uniform base + lane*16)
__device__ __forceinline__ void gl_lds16(const void* g, void* l) {
    __builtin_amdgcn_global_load_lds((const __attribute__((address_space(1))) void*)g,
                                     (__attribute__((address_space(3))) void*)l, 16, 0, 0);
}

// ================= prep: film2 | 4 transposes | ln_stats, one launch =================
__global__ __launch_bounds__(256) void prep_kernel(
    const float* __restrict__ x, float2* __restrict__ stats,
    const float* __restrict__ W_in, short* __restrict__ Wint,
    const float* __restrict__ W_out, short* __restrict__ Woutt,
    const float* __restrict__ W_x, short* __restrict__ Wxt,
    const float* __restrict__ W_dt, short* __restrict__ Wdtt,
    const float* __restrict__ cond,
    const float* __restrict__ gw, const float* __restrict__ gb,
    const float* __restrict__ bw, const float* __restrict__ bb,
    float* __restrict__ gamma, float* __restrict__ beta) {
    __shared__ __align__(16) float smem[2112];
    int bid = blockIdx.x;
    int tid = threadIdx.x;
    if (bid < 8) {
        float* cs = smem;            // [2][512]
        float* red = smem + 1024;    // [4][64][4]
        int d0 = bid * 64;
#pragma unroll
        for (int i = tid; i < 2 * C_ / 4; i += 256) {
            int b = i >> 7;
            int c4 = (i & 127) * 4;
            *(float4*)&cs[b * C_ + c4] = *(const float4*)(cond + (size_t)b * C_ + c4);
        }
        __syncthreads();
        int dl = tid & 63, ks = tid >> 6;
        int d = d0 + dl;
        float g0 = 0.f, g1 = 0.f, bt0 = 0.f, bt1 = 0.f;
#pragma unroll 4
        for (int k = ks * 128; k < ks * 128 + 128; k++) {
            float wg = gw[(size_t)k * D_ + d];
            float wb = bw[(size_t)k * D_ + d];
            float c0 = cs[k], c1 = cs[C_ + k];
            g0 = fmaf(c0, wg, g0);
            g1 = fmaf(c1, wg, g1);
            bt0 = fmaf(c0, wb, bt0);
            bt1 = fmaf(c1, wb, bt1);
        }
        red[(ks * 64 + dl) * 4 + 0] = g0; red[(ks * 64 + dl) * 4 + 1] = g1;
        red[(ks * 64 + dl) * 4 + 2] = bt0; red[(ks * 64 + dl) * 4 + 3] = bt1;
        __syncthreads();
        if (ks == 0) {
            float s0 = 0.f, s1 = 0.f, s2 = 0.f, s3 = 0.f;
#pragma unroll
            for (int q = 0; q < 4; q++) {
                s0 += red[(q * 64 + dl) * 4 + 0]; s1 += red[(q * 64 + dl) * 4 + 1];
                s2 += red[(q * 64 + dl) * 4 + 2]; s3 += red[(q * 64 + dl) * 4 + 3];
            }
            float gbv = gb[d], bbv = bb[d];
            gamma[d] = s0 + gbv;
            gamma[D_ + d] = s1 + gbv;
            beta[d] = s2 + bbv;
            beta[D_ + d] = s3 + bbv;
        }
    } else if (bid < 1640) {
        const float* W; short* Wt; int K, N, bx, by;
        int r = bid - 8;
        if (r < 1024)      { W = W_in;  Wt = Wint;  K = 512;  N = 2048; bx = r % 64; by = r / 64; }
        else if (r < 1536) { r -= 1024; W = W_out; Wt = Woutt; K = 1024; N = 512; bx = r % 16; by = r / 16; }
        else if (r < 1600) { r -= 1536; W = W_x;   Wt = Wxt;   K = 1024; N = 64;  bx = r % 2;  by = r / 2; }
        else               { r -= 1600; W = W_dt;  Wt = Wdtt;  K = 32;   N = 1024; bx = r;     by = 0; }
        float (*t)[33] = (float(*)[33])smem;
        int n0 = bx * 32, k0 = by * 32;
        int c = tid & 31, rr0 = tid >> 5;
#pragma unroll
        for (int rr = rr0; rr < 32; rr += 8)
            t[rr][c] = W[(size_t)(k0 + rr) * N + n0 + c];
        __syncthreads();
#pragma unroll
        for (int rr = rr0; rr < 32; rr += 8)
            Wt[(size_t)(n0 + rr) * K + k0 + c] = f2bf(t[c][rr]);
    } else {
        int t = bid - 1640;
        float2 v = *(const float2*)(x + (size_t)t * D_ + tid * 2);
        float s = v.x + v.y;
        float s2 = fmaf(v.x, v.x, v.y * v.y);
#pragma unroll
        for (int o = 32; o >= 1; o >>= 1) {
            s += __shfl_down(s, o);
            s2 += __shfl_down(s2, o);
        }
        int wid = tid >> 6;
        if ((tid & 63) == 0) { smem[wid] = s; smem[4 + wid] = s2; }
        __syncthreads();
        if (tid == 0) {
            float sum = smem[0] + smem[1] + smem[2] + smem[3];
            float sum2 = smem[4] + smem[5] + smem[6] + smem[7];
            float mu = sum * (1.f / (float)D_);
            float var = sum2 * (1.f / (float)D_) - mu * mu;
            stats[t] = make_float2(mu, rsqrtf(var + 1e-5f));
        }
    }
}

// ---------------- bf16 MFMA GEMM: C[M][N] = A[M][K] * Bt[N][K]^T ----------------
// LNA: A fp32 + LN in staging (reg-staged, padded LDS). Pure-copy operands use
// global_load_lds width-16 into LINEAR LDS (8 rows x 8 chunks = 64 lanes x 16B).
template <int BM, int BN, bool FILM, bool LNA, bool OBF>
__global__ __launch_bounds__(256) void gemm_bf16(
    const void* __restrict__ Av, const short* __restrict__ Bt, void* __restrict__ Cv,
    int M, int N, int K,
    const float2* __restrict__ stats, const float* __restrict__ lng, const float* __restrict__ lnb,
    const float* __restrict__ gamma, const float* __restrict__ beta) {
    constexpr int BK = 64;
    constexpr int LDA = LNA ? 72 : 64;   // padded only when reg-staged
    constexpr int LDB = 64;              // linear: required by global_load_lds
    constexpr int WM = BM / 2, WN = BN / 2;
    constexpr int MR = WM / 32, NR = WN / 32;
    __shared__ __align__(16) short As[BM * LDA];
    __shared__ __align__(16) short Bs[BN * LDB];
    int tid = threadIdx.x;
    int lane = tid & 63, w = tid >> 6;
    int wr = w >> 1, wc = w & 1;
    int m0 = blockIdx.y * BM, n0 = blockIdx.x * BN;
    int lr = lane >> 3, lc = lane & 7;   // gload_lds: lane -> (row-in-chunk, 16B-col)

    f32x16 acc[MR][NR];
#pragma unroll
    for (int i = 0; i < MR; i++)
#pragma unroll
        for (int j = 0; j < NR; j++)
#pragma unroll
            for (int r = 0; r < 16; r++) acc[i][j][r] = 0.f;

    int l31 = lane & 31, hk = (lane >> 5) * 8;

    for (int k0 = 0; k0 < K; k0 += BK) {
        __syncthreads();
        if constexpr (LNA) {
            const float* Af = (const float*)Av;
#pragma unroll
            for (int i = tid; i < BM * 8; i += 256) {
                int r = i >> 3, c = (i & 7) * 8;
                float2 st = stats[m0 + r];
                const float* src = Af + (size_t)(m0 + r) * K + k0 + c;
                float4 v0 = *(const float4*)src;
                float4 v1 = *(const float4*)(src + 4);
                float4 g0 = *(const float4*)(lng + k0 + c);
                float4 g1 = *(const float4*)(lng + k0 + c + 4);
                float4 b0 = *(const float4*)(lnb + k0 + c);
                float4 b1 = *(const float4*)(lnb + k0 + c + 4);
                short8 o;
                o[0] = f2bf((v0.x - st.x) * st.y * g0.x + b0.x);
                o[1] = f2bf((v0.y - st.x) * st.y * g0.y + b0.y);
                o[2] = f2bf((v0.z - st.x) * st.y * g0.z + b0.z);
                o[3] = f2bf((v0.w - st.x) * st.y * g0.w + b0.w);
                o[4] = f2bf((v1.x - st.x) * st.y * g1.x + b1.x);
                o[5] = f2bf((v1.y - st.x) * st.y * g1.y + b1.y);
                o[6] = f2bf((v1.z - st.x) * st.y * g1.z + b1.z);
                o[7] = f2bf((v1.w - st.x) * st.y * g1.w + b1.w);
                *(short8*)&As[r * LDA + c] = o;
            }
        } else {
            const short* Ab = (const short*)Av;
#pragma unroll
            for (int ch = w; ch < BM / 8; ch += 4)
                gl_lds16(&Ab[(size_t)(m0 + ch * 8 + lr) * K + k0 + lc * 8], &As[ch * 512]);
        }
#pragma unroll
        for (int ch = w; ch < BN / 8; ch += 4)
            gl_lds16(&Bt[(size_t)(n0 + ch * 8 + lr) * K + k0 + lc * 8], &Bs[ch * 512]);
        __syncthreads();   // drains vmcnt (gload_lds) + lgkmcnt (ds_write)
#pragma unroll
        for (int kk = 0; kk < 4; kk++) {
            short8 a[MR], b[NR];
#pragma unroll
            for (int i = 0; i < MR; i++)
                a[i] = *(const short8*)&As[(wr * WM + i * 32 + l31) * LDA + kk * 16 + hk];
#pragma unroll
            for (int j = 0; j < NR; j++)
                b[j] = *(const short8*)&Bs[(wc * WN + j * 32 + l31) * LDB + kk * 16 + hk];
#pragma unroll
            for (int i = 0; i < MR; i++)
#pragma unroll
                for (int j = 0; j < NR; j++)
                    acc[i][j] = __builtin_amdgcn_mfma_f32_32x32x16_bf16(a[i], b[j], acc[i][j], 0, 0, 0);
        }
    }
    int rbase = 4 * (lane >> 5);
    int bi = m0 >> 11;   // batch index
#pragma unroll
    for (int i = 0; i < MR; i++)
#pragma unroll
        for (int j = 0; j < NR; j++) {
            int col = n0 + wc * WN + j * 32 + l31;
            float gm = 1.f, bt = 0.f;
            if (FILM) {
                gm = gamma[bi * D_ + col];
                bt = beta[bi * D_ + col];
            }
#pragma unroll
            for (int r = 0; r < 16; r++) {
                int row = m0 + wr * WM + i * 32 + rbase + (r & 3) + 8 * (r >> 2);
                float v = acc[i][j][r];
                if (FILM) v = gm * v + bt;
                if constexpr (OBF)
                    ((short*)Cv)[(size_t)row * N + col] = f2bf(v);
                else
                    ((float*)Cv)[(size_t)row * N + col] = v;
            }
        }
}

// ================= mid: conv+SiLU -> xproj -> dt; 8 tokens/block, 4 waves, 512 blocks =================
__global__ __launch_bounds__(256) void mid_kernel(
    const short* __restrict__ xzb, const float* __restrict__ cw, const float* __restrict__ cb,
    const short* __restrict__ Wxt,   // [64][1024] bf16
    const short* __restrict__ Wdtt,  // [1024][32] bf16
    const float* __restrict__ bdt,
    short* __restrict__ ucb, float* __restrict__ xdbl, short* __restrict__ deltab) {
    constexpr int LDU = 1032;
    __shared__ __align__(16) short u[16 * LDU];   // rows 0..10 staged (3 halo + 8 tokens)
    __shared__ __align__(16) float xd[16 * 68];
    int tid = threadIdx.x;
    int t0 = blockIdx.x * 8;
    int n0 = t0 & (N_ - 1);
    for (int i = tid; i < 11 * 128; i += 256) {
        int r = i >> 7, c8 = (i & 127) * 8;
        short8 v = {0, 0, 0, 0, 0, 0, 0, 0};
        if (n0 + r - 3 >= 0)
            v = *(const short8*)&xzb[(size_t)(t0 + r - 3) * (2 * E_) + c8];
        *(short8*)&u[r * LDU + c8] = v;
    }
    __syncthreads();
#pragma unroll
    for (int q = 0; q < 4; q++) {
        int e = tid + q * 256;
        float4 cwv = *(const float4*)(cw + e * 4);
        float cbv = cb[e];
        float u0 = bf2f(u[0 * LDU + e]);
        float u1 = bf2f(u[1 * LDU + e]);
        float u2 = bf2f(u[2 * LDU + e]);
#pragma unroll
        for (int n = 0; n < 8; n++) {
            float u3 = bf2f(u[(n + 3) * LDU + e]);
            float a = fmaf(cwv.x, u0, fmaf(cwv.y, u1, fmaf(cwv.z, u2, fmaf(cwv.w, u3, cbv))));
            float v = a / (1.f + __expf(-a));
            short vb = f2bf(v);
            ucb[(size_t)(t0 + n) * E_ + e] = vb;
            u[n * LDU + e] = vb;
            u0 = u1; u1 = u2; u2 = u3;
        }
    }
    __syncthreads();
    int lane = tid & 63, w = tid >> 6;
    int l15 = lane & 15, kq = (lane >> 4) * 8;
    // xproj: wave w -> x_dbl cols [w*16, w*16+16), full K=1024 (A rows 8..15 junk, discarded)
    f32x4 acc4 = {0.f, 0.f, 0.f, 0.f};
#pragma unroll 8
    for (int k0 = 0; k0 < 32; k0++) {
        short8 af = *(const short8*)&u[l15 * LDU + k0 * 32 + kq];
        short8 bfr = *(const short8*)&Wxt[(size_t)(w * 16 + l15) * E_ + k0 * 32 + kq];
        acc4 = __builtin_amdgcn_mfma_f32_16x16x32_bf16(af, bfr, acc4, 0, 0, 0);
    }
#pragma unroll
    for (int j = 0; j < 4; j++)
        xd[((lane >> 4) * 4 + j) * 68 + w * 16 + l15] = acc4[j];
    __syncthreads();
    if (tid < 128) {
        int r = tid >> 4, c4 = (tid & 15) * 4;
        *(float4*)&xdbl[(size_t)(t0 + r) * 64 + c4] = *(const float4*)&xd[r * 68 + c4];
    }
    // dt: 4 waves x 16 e-tiles; valid output rows 0..7
    float av[8];
    *(float4*)&av[0] = *(const float4*)&xd[l15 * 68 + kq];
    *(float4*)&av[4] = *(const float4*)&xd[l15 * 68 + kq + 4];
    short8 ab;
#pragma unroll
    for (int j = 0; j < 8; j++) ab[j] = f2bf(av[j]);
    int row4 = (lane >> 4) * 4;
#pragma unroll 4
    for (int t = 0; t < 16; t++) {
        int e = w * 256 + t * 16 + l15;
        short8 bb = *(const short8*)&Wdtt[(size_t)e * 32 + kq];
        f32x4 c4v = {0.f, 0.f, 0.f, 0.f};
        c4v = __builtin_amdgcn_mfma_f32_16x16x32_bf16(ab, bb, c4v, 0, 0, 0);
        if (row4 < 8) {
            float bv = bdt[e];
#pragma unroll
            for (int j = 0; j < 4; j++) {
                float xv = c4v[j] + bv;
                float sp = (xv > 20.f) ? xv : log1pf(__expf(xv));
                deltab[(size_t)(t0 + row4 + j) * E_ + e] = f2bf(sp);
            }
        }
    }
}

// ---------------- chunked selective scan, s-in-registers (bf16 inputs) ----------------
__global__ __launch_bounds__(256) void scan_p1(const short* __restrict__ deltab,
                                               const short* __restrict__ ucb,
                                               const float* __restrict__ xdbl,
                                               const float* __restrict__ A_log,
                                               float* __restrict__ hend,
                                               float* __restrict__ cumd) {
    int blk = blockIdx.x;            // b*(NC_*4) + c*4 + eq
    int eq = blk & 3;
    int c = (blk >> 2) & (NC_ - 1);
    int b = blk >> 8;
    int tid = threadIdx.x;
    int e = eq * 256 + tid;
    __shared__ float Bsl[CH_][16];
    int base = (b * N_ + c * CH_) * 64;
    for (int i = tid; i < CH_ * 16; i += 256) {
        int n = i >> 4, col = i & 15;
        Bsl[n][col] = xdbl[base + n * 64 + R_ + col];
    }
    float Aes[16];
    const float4* al = (const float4*)(A_log + e * 16);
#pragma unroll
    for (int j = 0; j < 4; j++) {
        float4 a = al[j];
        Aes[j * 4 + 0] = -__expf(a.x);
        Aes[j * 4 + 1] = -__expf(a.y);
        Aes[j * 4 + 2] = -__expf(a.z);
        Aes[j * 4 + 3] = -__expf(a.w);
    }
    __syncthreads();
    float h[16];
#pragma unroll
    for (int s = 0; s < 16; s++) h[s] = 0.f;
    float cum = 0.f;
    const short* dp = deltab + (size_t)(b * N_ + c * CH_) * E_ + e;
    const short* up = ucb + (size_t)(b * N_ + c * CH_) * E_ + e;
#pragma unroll 2
    for (int n = 0; n < CH_; n++) {
        float dv = bf2f(dp[n * E_]);
        float uv = bf2f(up[n * E_]);
        float du = dv * uv;
        cum += dv;
        float Bl[16];
#pragma unroll
        for (int j = 0; j < 4; j++) *(float4*)&Bl[j * 4] = *(const float4*)&Bsl[n][j * 4];
#pragma unroll
        for (int s = 0; s < 16; s++) {
            float dA = __expf(dv * Aes[s]);
            h[s] = fmaf(dA, h[s], du * Bl[s]);
        }
    }
    size_t ob = (size_t)(b * NC_ + c) * 16 * E_ + e;
#pragma unroll
    for (int s = 0; s < 16; s++) hend[ob + (size_t)s * E_] = h[s];
    cumd[(size_t)(b * NC_ + c) * E_ + e] = cum;
}

__global__ __launch_bounds__(256) void scan_comb(float* __restrict__ hend,
                                                 const float* __restrict__ cumd,
                                                 const float* __restrict__ A_log) {
    int idx = blockIdx.x * 256 + threadIdx.x;   // over B*S*E = 32768
    int b = idx >> 14;
    int s = (idx >> 10) & 15;
    int e = idx & 1023;
    float Aes = -__expf(A_log[e * 16 + s]);
    float h = 0.f;
#pragma unroll 4
    for (int c = 0; c < NC_; c++) {
        size_t i = ((size_t)((b * NC_ + c) * 16) + s) * E_ + e;
        float he = hend[i];
        float P = __expf(Aes * cumd[(size_t)(b * NC_ + c) * E_ + e]);
        hend[i] = h;
        h = fmaf(P, h, he);
    }
}

__global__ __launch_bounds__(256) void scan_p3(const short* __restrict__ deltab,
                                               const short* __restrict__ ucb,
                                               const float* __restrict__ xdbl,
                                               const short* __restrict__ xzb,
                                               const float* __restrict__ A_log,
                                               const float* __restrict__ D_skip,
                                               const float* __restrict__ hend,
                                               short* __restrict__ yb) {
    int blk = blockIdx.x;
    int eq = blk & 3;
    int c = (blk >> 2) & (NC_ - 1);
    int b = blk >> 8;
    int tid = threadIdx.x;
    int e = eq * 256 + tid;
    __shared__ float Bsl[CH_][16];
    __shared__ float Csl[CH_][16];
    int base = (b * N_ + c * CH_) * 64;
    for (int i = tid; i < CH_ * 32; i += 256) {
        int n = i >> 5, col = i & 31;
        float v = xdbl[base + n * 64 + R_ + col];
        if (col < 16) Bsl[n][col] = v;
        else Csl[n][col - 16] = v;
    }
    float Aes[16];
    const float4* al = (const float4*)(A_log + e * 16);
#pragma unroll
    for (int j = 0; j < 4; j++) {
        float4 a = al[j];
        Aes[j * 4 + 0] = -__expf(a.x);
        Aes[j * 4 + 1] = -__expf(a.y);
        Aes[j * 4 + 2] = -__expf(a.z);
        Aes[j * 4 + 3] = -__expf(a.w);
    }
    float dsk = D_skip[e];
    float h[16];
    size_t ob = (size_t)(b * NC_ + c) * 16 * E_ + e;
#pragma unroll
    for (int s = 0; s < 16; s++) h[s] = hend[ob + (size_t)s * E_];
    __syncthreads();
    const short* dp = deltab + (size_t)(b * N_ + c * CH_) * E_ + e;
    const short* up = ucb + (size_t)(b * N_ + c * CH_) * E_ + e;
    const short* zp = xzb + (size_t)(b * N_ + c * CH_) * (2 * E_) + E_ + e;
    short* yp = yb + (size_t)(b * N_ + c * CH_) * E_ + e;
#pragma unroll 2
    for (int n = 0; n < CH_; n++) {
        float dv = bf2f(dp[n * E_]);
        float uv = bf2f(up[n * E_]);
        float du = dv * uv;
        float Bl[16], Cl[16];
#pragma unroll
        for (int j = 0; j < 4; j++) {
            *(float4*)&Bl[j * 4] = *(const float4*)&Bsl[n][j * 4];
            *(float4*)&Cl[j * 4] = *(const float4*)&Csl[n][j * 4];
        }
        float y = 0.f;
#pragma unroll
        for (int s = 0; s < 16; s++) {
            float dA = __expf(dv * Aes[s]);
            h[s] = fmaf(dA, h[s], du * Bl[s]);
            y = fmaf(h[s], Cl[s], y);
        }
        float zv = bf2f(zp[n * 2 * E_]);
        float yy = y + dsk * uv;
        yy = yy * (zv / (1.f + __expf(-zv)));
        yp[n * E_] = f2bf(yy);
    }
}

extern "C" void kernel_launch(void* const* d_in, const int* in_sizes, int n_in,
                              void* d_out, int out_size, void* d_ws, size_t ws_size,
                              hipStream_t stream) {
    const float* x       = (const float*)d_in[0];
    const float* cond    = (const float*)d_in[1];
    const float* ln_g    = (const float*)d_in[2];
    const float* ln_b    = (const float*)d_in[3];
    const float* W_in    = (const float*)d_in[4];
    const float* conv_w  = (const float*)d_in[5];
    const float* conv_b  = (const float*)d_in[6];
    const float* W_x     = (const float*)d_in[7];
    const float* W_dt    = (const float*)d_in[8];
    const float* b_dt    = (const float*)d_in[9];
    const float* A_log   = (const float*)d_in[10];
    const float* D_skip  = (const float*)d_in[11];
    const float* W_out   = (const float*)d_in[12];
    const float* film_gw = (const float*)d_in[13];
    const float* film_gb = (const float*)d_in[14];
    const float* film_bw = (const float*)d_in[15];
    const float* film_bb = (const float*)d_in[16];
    float* out = (float*)d_out;

    float* ws = (float*)d_ws;
    float* xdbl  = ws;                       //   262,144 f
    float* gamma = xdbl + 262144;            //     1,024 f
    float* beta  = gamma + 1024;             //     1,024 f
    float2* stats = (float2*)(beta + 1024);  //     4,096 f2
    float* hend  = (float*)(stats + 4096);   // 2,097,152 f  (B*NC*S*E)
    float* cumd  = hend + 2097152;           //   131,072 f  (B*NC*E)
    short* xzb   = (short*)(cumd + 131072);  // 8,388,608 sh (bf16 xz)
    short* ucb   = xzb + 8388608;            // 4,194,304 sh (bf16 uc)
    short* deltab = ucb + 4194304;           // 4,194,304 sh (bf16 delta)
    short* Wint  = deltab + 4194304;         // 1,048,576 sh
    short* Woutt = Wint + 1048576;           //   524,288 sh
    short* yb    = Woutt + 524288;           // 4,194,304 sh
    short* Wxt   = yb + 4194304;             //    65,536 sh
    short* Wdtt  = Wxt + 65536;              //    32,768 sh

    // prep: film2 + 4 weight transposes + ln_stats, one launch (5736 blocks)
    prep_kernel<<<5736, 256, 0, stream>>>(
        x, stats, W_in, Wint, W_out, Woutt, W_x, Wxt, W_dt, Wdtt,
        cond, film_gw, film_gb, film_bw, film_bb, gamma, beta);

    // xz = LN(x) @ W_in   [4096,512]x[512,2048], LN fused, bf16 output
    gemm_bf16<128, 128, false, true, true>
        <<<dim3(2 * E_ / 128, B_ * N_ / 128), 256, 0, stream>>>(
            x, Wint, xzb, B_ * N_, 2 * E_, D_, stats, ln_g, ln_b, nullptr, nullptr);

    // conv+silu -> xproj -> dt, fused; 512 blocks x 4 waves, 8 tokens each
    mid_kernel<<<B_ * N_ / 8, 256, 0, stream>>>(
        xzb, conv_w, conv_b, Wxt, Wdtt, b_dt, ucb, xdbl, deltab);

    scan_p1<<<B_ * NC_ * 4, 256, 0, stream>>>(deltab, ucb, xdbl, A_log, hend, cumd);
    scan_comb<<<(B_ * S_ * E_) / 256, 256, 0, stream>>>(hend, cumd, A_log);
    scan_p3<<<B_ * NC_ * 4, 256, 0, stream>>>(deltab, ucb, xdbl, xzb, A_log, D_skip, hend, yb);

    // out = FiLM(y @ W_out)   [4096,1024]x[1024,512], fp32 output
    gemm_bf16<128, 64, true, false, false>
        <<<dim3(D_ / 64, B_ * N_ / 128), 256, 0, stream>>>(
            yb, Woutt, out, B_ * N_, D_, E_, nullptr, nullptr, nullptr, gamma, beta);
}

// Round 11
// 151.273 us; speedup vs baseline: 3.9118x; 1.1100x over previous
//
#include <hip/hip_runtime.h>
#include <hip/hip_bf16.h>
#include <math.h>

#define B_ 2
#define N_ 2048
#define D_ 512
#define E_ 1024
#define S_ 16
#define R_ 32
#define C_ 512
#define CH_ 32
#define NC_ (N_ / CH_)   // 64 chunks

using short8 = __attribute__((ext_vector_type(8))) short;
using f32x4  = __attribute__((ext_vector_type(4))) float;
using f32x16 = __attribute__((ext_vector_type(16))) float;

__device__ __forceinline__ short f2bf(float f) {
    union { float f; unsigned u; } x; x.f = f;
    unsigned r = (x.u + 0x7fffu + ((x.u >> 16) & 1u)) >> 16;
    return (short)r;
}
__device__ __forceinline__ float bf2f(short s) {
    union { unsigned u; float f; } x;
    x.u = ((unsigned)(unsigned short)s) << 16;
    return x.f;
}
// wave-level async global->LDS, 16B per lane (lds dest wave-uniform base + lane*16)
__device__ __forceinline__ void gl_lds16(const void* g, void* l) {
    __builtin_amdgcn_global_load_lds((const __attribute__((address_space(1))) void*)g,
                                     (__attribute__((address_space(3))) void*)l, 16, 0, 0);
}

// ================= prep: film2 | 4 transposes | ln_stats, one launch =================
__global__ __launch_bounds__(256) void prep_kernel(
    const float* __restrict__ x, float2* __restrict__ stats,
    const float* __restrict__ W_in, short* __restrict__ Wint,
    const float* __restrict__ W_out, short* __restrict__ Woutt,
    const float* __restrict__ W_x, short* __restrict__ Wxt,
    const float* __restrict__ W_dt, short* __restrict__ Wdtt,
    const float* __restrict__ cond,
    const float* __restrict__ gw, const float* __restrict__ gb,
    const float* __restrict__ bw, const float* __restrict__ bb,
    float* __restrict__ gamma, float* __restrict__ beta) {
    __shared__ __align__(16) float smem[2112];
    int bid = blockIdx.x;
    int tid = threadIdx.x;
    if (bid < 8) {
        float* cs = smem;            // [2][512]
        float* red = smem + 1024;    // [4][64][4]
        int d0 = bid * 64;
#pragma unroll
        for (int i = tid; i < 2 * C_ / 4; i += 256) {
            int b = i >> 7;
            int c4 = (i & 127) * 4;
            *(float4*)&cs[b * C_ + c4] = *(const float4*)(cond + (size_t)b * C_ + c4);
        }
        __syncthreads();
        int dl = tid & 63, ks = tid >> 6;
        int d = d0 + dl;
        float g0 = 0.f, g1 = 0.f, bt0 = 0.f, bt1 = 0.f;
#pragma unroll 4
        for (int k = ks * 128; k < ks * 128 + 128; k++) {
            float wg = gw[(size_t)k * D_ + d];
            float wb = bw[(size_t)k * D_ + d];
            float c0 = cs[k], c1 = cs[C_ + k];
            g0 = fmaf(c0, wg, g0);
            g1 = fmaf(c1, wg, g1);
            bt0 = fmaf(c0, wb, bt0);
            bt1 = fmaf(c1, wb, bt1);
        }
        red[(ks * 64 + dl) * 4 + 0] = g0; red[(ks * 64 + dl) * 4 + 1] = g1;
        red[(ks * 64 + dl) * 4 + 2] = bt0; red[(ks * 64 + dl) * 4 + 3] = bt1;
        __syncthreads();
        if (ks == 0) {
            float s0 = 0.f, s1 = 0.f, s2 = 0.f, s3 = 0.f;
#pragma unroll
            for (int q = 0; q < 4; q++) {
                s0 += red[(q * 64 + dl) * 4 + 0]; s1 += red[(q * 64 + dl) * 4 + 1];
                s2 += red[(q * 64 + dl) * 4 + 2]; s3 += red[(q * 64 + dl) * 4 + 3];
            }
            float gbv = gb[d], bbv = bb[d];
            gamma[d] = s0 + gbv;
            gamma[D_ + d] = s1 + gbv;
            beta[d] = s2 + bbv;
            beta[D_ + d] = s3 + bbv;
        }
    } else if (bid < 1640) {
        const float* W; short* Wt; int K, N, bx, by;
        int r = bid - 8;
        if (r < 1024)      { W = W_in;  Wt = Wint;  K = 512;  N = 2048; bx = r % 64; by = r / 64; }
        else if (r < 1536) { r -= 1024; W = W_out; Wt = Woutt; K = 1024; N = 512; bx = r % 16; by = r / 16; }
        else if (r < 1600) { r -= 1536; W = W_x;   Wt = Wxt;   K = 1024; N = 64;  bx = r % 2;  by = r / 2; }
        else               { r -= 1600; W = W_dt;  Wt = Wdtt;  K = 32;   N = 1024; bx = r;     by = 0; }
        float (*t)[33] = (float(*)[33])smem;
        int n0 = bx * 32, k0 = by * 32;
        int c = tid & 31, rr0 = tid >> 5;
#pragma unroll
        for (int rr = rr0; rr < 32; rr += 8)
            t[rr][c] = W[(size_t)(k0 + rr) * N + n0 + c];
        __syncthreads();
#pragma unroll
        for (int rr = rr0; rr < 32; rr += 8)
            Wt[(size_t)(n0 + rr) * K + k0 + c] = f2bf(t[c][rr]);
    } else {
        int t = bid - 1640;
        float2 v = *(const float2*)(x + (size_t)t * D_ + tid * 2);
        float s = v.x + v.y;
        float s2 = fmaf(v.x, v.x, v.y * v.y);
#pragma unroll
        for (int o = 32; o >= 1; o >>= 1) {
            s += __shfl_down(s, o);
            s2 += __shfl_down(s2, o);
        }
        int wid = tid >> 6;
        if ((tid & 63) == 0) { smem[wid] = s; smem[4 + wid] = s2; }
        __syncthreads();
        if (tid == 0) {
            float sum = smem[0] + smem[1] + smem[2] + smem[3];
            float sum2 = smem[4] + smem[5] + smem[6] + smem[7];
            float mu = sum * (1.f / (float)D_);
            float var = sum2 * (1.f / (float)D_) - mu * mu;
            stats[t] = make_float2(mu, rsqrtf(var + 1e-5f));
        }
    }
}

// ---------------- bf16 MFMA GEMM: C[M][N] = A[M][K] * Bt[N][K]^T ----------------
// LNA: A fp32 + LN in staging (reg-staged, padded LDS). Pure-copy operands use
// global_load_lds width-16 into LINEAR LDS (8 rows x 8 chunks = 64 lanes x 16B).
template <int BM, int BN, bool FILM, bool LNA, bool OBF>
__global__ __launch_bounds__(256) void gemm_bf16(
    const void* __restrict__ Av, const short* __restrict__ Bt, void* __restrict__ Cv,
    int M, int N, int K,
    const float2* __restrict__ stats, const float* __restrict__ lng, const float* __restrict__ lnb,
    const float* __restrict__ gamma, const float* __restrict__ beta) {
    constexpr int BK = 64;
    constexpr int LDA = LNA ? 72 : 64;   // padded only when reg-staged
    constexpr int LDB = 64;              // linear: required by global_load_lds
    constexpr int WM = BM / 2, WN = BN / 2;
    constexpr int MR = WM / 32, NR = WN / 32;
    __shared__ __align__(16) short As[BM * LDA];
    __shared__ __align__(16) short Bs[BN * LDB];
    int tid = threadIdx.x;
    int lane = tid & 63, w = tid >> 6;
    int wr = w >> 1, wc = w & 1;
    int m0 = blockIdx.y * BM, n0 = blockIdx.x * BN;
    int lr = lane >> 3, lc = lane & 7;   // gload_lds: lane -> (row-in-chunk, 16B-col)

    f32x16 acc[MR][NR];
#pragma unroll
    for (int i = 0; i < MR; i++)
#pragma unroll
        for (int j = 0; j < NR; j++)
#pragma unroll
            for (int r = 0; r < 16; r++) acc[i][j][r] = 0.f;

    int l31 = lane & 31, hk = (lane >> 5) * 8;

    for (int k0 = 0; k0 < K; k0 += BK) {
        __syncthreads();
        if constexpr (LNA) {
            const float* Af = (const float*)Av;
#pragma unroll
            for (int i = tid; i < BM * 8; i += 256) {
                int r = i >> 3, c = (i & 7) * 8;
                float2 st = stats[m0 + r];
                const float* src = Af + (size_t)(m0 + r) * K + k0 + c;
                float4 v0 = *(const float4*)src;
                float4 v1 = *(const float4*)(src + 4);
                float4 g0 = *(const float4*)(lng + k0 + c);
                float4 g1 = *(const float4*)(lng + k0 + c + 4);
                float4 b0 = *(const float4*)(lnb + k0 + c);
                float4 b1 = *(const float4*)(lnb + k0 + c + 4);
                short8 o;
                o[0] = f2bf((v0.x - st.x) * st.y * g0.x + b0.x);
                o[1] = f2bf((v0.y - st.x) * st.y * g0.y + b0.y);
                o[2] = f2bf((v0.z - st.x) * st.y * g0.z + b0.z);
                o[3] = f2bf((v0.w - st.x) * st.y * g0.w + b0.w);
                o[4] = f2bf((v1.x - st.x) * st.y * g1.x + b1.x);
                o[5] = f2bf((v1.y - st.x) * st.y * g1.y + b1.y);
                o[6] = f2bf((v1.z - st.x) * st.y * g1.z + b1.z);
                o[7] = f2bf((v1.w - st.x) * st.y * g1.w + b1.w);
                *(short8*)&As[r * LDA + c] = o;
            }
        } else {
            const short* Ab = (const short*)Av;
#pragma unroll
            for (int ch = w; ch < BM / 8; ch += 4)
                gl_lds16(&Ab[(size_t)(m0 + ch * 8 + lr) * K + k0 + lc * 8], &As[ch * 512]);
        }
#pragma unroll
        for (int ch = w; ch < BN / 8; ch += 4)
            gl_lds16(&Bt[(size_t)(n0 + ch * 8 + lr) * K + k0 + lc * 8], &Bs[ch * 512]);
        __syncthreads();   // drains vmcnt (gload_lds) + lgkmcnt (ds_write)
#pragma unroll
        for (int kk = 0; kk < 4; kk++) {
            short8 a[MR], b[NR];
#pragma unroll
            for (int i = 0; i < MR; i++)
                a[i] = *(const short8*)&As[(wr * WM + i * 32 + l31) * LDA + kk * 16 + hk];
#pragma unroll
            for (int j = 0; j < NR; j++)
                b[j] = *(const short8*)&Bs[(wc * WN + j * 32 + l31) * LDB + kk * 16 + hk];
#pragma unroll
            for (int i = 0; i < MR; i++)
#pragma unroll
                for (int j = 0; j < NR; j++)
                    acc[i][j] = __builtin_amdgcn_mfma_f32_32x32x16_bf16(a[i], b[j], acc[i][j], 0, 0, 0);
        }
    }
    int rbase = 4 * (lane >> 5);
    int bi = m0 >> 11;   // batch index
#pragma unroll
    for (int i = 0; i < MR; i++)
#pragma unroll
        for (int j = 0; j < NR; j++) {
            int col = n0 + wc * WN + j * 32 + l31;
            float gm = 1.f, bt = 0.f;
            if (FILM) {
                gm = gamma[bi * D_ + col];
                bt = beta[bi * D_ + col];
            }
#pragma unroll
            for (int r = 0; r < 16; r++) {
                int row = m0 + wr * WM + i * 32 + rbase + (r & 3) + 8 * (r >> 2);
                float v = acc[i][j][r];
                if (FILM) v = gm * v + bt;
                if constexpr (OBF)
                    ((short*)Cv)[(size_t)row * N + col] = f2bf(v);
                else
                    ((float*)Cv)[(size_t)row * N + col] = v;
            }
        }
}

// ================= mid v3: parallel conv (register, no halo LDS) -> xproj -> dt =================
// 16 tokens/block, 512 threads (8 waves), 256 blocks.
__global__ __launch_bounds__(512) void mid_kernel(
    const short* __restrict__ xzb, const float* __restrict__ cw, const float* __restrict__ cb,
    const short* __restrict__ Wxt,   // [64][1024] bf16
    const short* __restrict__ Wdtt,  // [1024][32] bf16
    const float* __restrict__ bdt,
    short* __restrict__ ucb, float* __restrict__ xdbl, short* __restrict__ deltab) {
    constexpr int LDU = 1032;                        // 2064B pitch
    __shared__ __align__(16) short u[16 * LDU];      // 33 KB uc (bf16)
    __shared__ __align__(16) float xd2[2][16 * 68];  // 8.7 KB x_dbl partials
    int tid = threadIdx.x;
    int t0 = blockIdx.x * 16;
    int n0 = t0 & (N_ - 1);
    // ---- conv+SiLU, fully parallel: thread -> fixed e-chunk (8 wide), 4 tokens ----
    {
        int c8 = (tid & 127) * 8;      // e offset
        int ng = tid >> 7;             // 0..3
        float4 wv[8];
        float cbv[8];
#pragma unroll
        for (int j = 0; j < 8; j++) {
            wv[j] = *(const float4*)(cw + (c8 + j) * 4);
            cbv[j] = cb[c8 + j];
        }
#pragma unroll
        for (int k = 0; k < 4; k++) {
            int n = ng * 4 + k;        // token in block
            float uf[4][8];
#pragma unroll
            for (int j = 0; j < 4; j++) {
                short8 v = {0, 0, 0, 0, 0, 0, 0, 0};
                if (n0 + n - 3 + j >= 0)
                    v = *(const short8*)&xzb[(size_t)(t0 + n - 3 + j) * (2 * E_) + c8];
#pragma unroll
                for (int q = 0; q < 8; q++) uf[j][q] = bf2f(v[q]);
            }
            short8 o;
#pragma unroll
            for (int q = 0; q < 8; q++) {
                float a = fmaf(wv[q].x, uf[0][q],
                          fmaf(wv[q].y, uf[1][q],
                          fmaf(wv[q].z, uf[2][q],
                          fmaf(wv[q].w, uf[3][q], cbv[q]))));
                float v = a / (1.f + __expf(-a));
                o[q] = f2bf(v);
            }
            *(short8*)&ucb[(size_t)(t0 + n) * E_ + c8] = o;
            *(short8*)&u[n * LDU + c8] = o;
        }
    }
    __syncthreads();
    // ---- xproj: 8 waves; wave w -> cols [cg*16,+16), K-half kh; partials in xd2[kh] ----
    int lane = tid & 63, w = tid >> 6;
    int cg = w & 3, kh = w >> 2;
    int l15 = lane & 15, kq = (lane >> 4) * 8;
    f32x4 acc4 = {0.f, 0.f, 0.f, 0.f};
#pragma unroll 8
    for (int k0 = 0; k0 < 16; k0++) {
        int kk = kh * 512 + k0 * 32;
        short8 af = *(const short8*)&u[l15 * LDU + kk + kq];
        short8 bfr = *(const short8*)&Wxt[(size_t)(cg * 16 + l15) * E_ + kk + kq];
        acc4 = __builtin_amdgcn_mfma_f32_16x16x32_bf16(af, bfr, acc4, 0, 0, 0);
    }
#pragma unroll
    for (int j = 0; j < 4; j++)
        xd2[kh][((lane >> 4) * 4 + j) * 68 + cg * 16 + l15] = acc4[j];
    __syncthreads();
    // reduce K-halves, write x_dbl, keep sum in xd2[0]
    if (tid < 256) {
        int r = tid >> 4, c4 = (tid & 15) * 4;
        float4 a = *(const float4*)&xd2[0][r * 68 + c4];
        float4 b = *(const float4*)&xd2[1][r * 68 + c4];
        a.x += b.x; a.y += b.y; a.z += b.z; a.w += b.w;
        *(float4*)&xd2[0][r * 68 + c4] = a;
        *(float4*)&xdbl[(size_t)(t0 + r) * 64 + c4] = a;
    }
    __syncthreads();
    // ---- dt: 8 waves x 8 e-tiles of 16; all 16 rows valid ----
    float av[8];
    *(float4*)&av[0] = *(const float4*)&xd2[0][l15 * 68 + kq];
    *(float4*)&av[4] = *(const float4*)&xd2[0][l15 * 68 + kq + 4];
    short8 ab;
#pragma unroll
    for (int j = 0; j < 8; j++) ab[j] = f2bf(av[j]);
    int row4 = (lane >> 4) * 4;
#pragma unroll 4
    for (int t = 0; t < 8; t++) {
        int e = w * 128 + t * 16 + l15;
        short8 bb = *(const short8*)&Wdtt[(size_t)e * 32 + kq];
        f32x4 c4v = {0.f, 0.f, 0.f, 0.f};
        c4v = __builtin_amdgcn_mfma_f32_16x16x32_bf16(ab, bb, c4v, 0, 0, 0);
        float bv = bdt[e];
#pragma unroll
        for (int j = 0; j < 4; j++) {
            float xv = c4v[j] + bv;
            float sp = (xv > 20.f) ? xv : log1pf(__expf(xv));
            deltab[(size_t)(t0 + row4 + j) * E_ + e] = f2bf(sp);
        }
    }
}

// ---------------- chunked selective scan, s-in-registers (bf16 inputs) ----------------
__global__ __launch_bounds__(256) void scan_p1(const short* __restrict__ deltab,
                                               const short* __restrict__ ucb,
                                               const float* __restrict__ xdbl,
                                               const float* __restrict__ A_log,
                                               float* __restrict__ hend,
                                               float* __restrict__ cumd) {
    int blk = blockIdx.x;            // b*(NC_*4) + c*4 + eq
    int eq = blk & 3;
    int c = (blk >> 2) & (NC_ - 1);
    int b = blk >> 8;
    int tid = threadIdx.x;
    int e = eq * 256 + tid;
    __shared__ float Bsl[CH_][16];
    int base = (b * N_ + c * CH_) * 64;
    for (int i = tid; i < CH_ * 16; i += 256) {
        int n = i >> 4, col = i & 15;
        Bsl[n][col] = xdbl[base + n * 64 + R_ + col];
    }
    float Aes[16];
    const float4* al = (const float4*)(A_log + e * 16);
#pragma unroll
    for (int j = 0; j < 4; j++) {
        float4 a = al[j];
        Aes[j * 4 + 0] = -__expf(a.x);
        Aes[j * 4 + 1] = -__expf(a.y);
        Aes[j * 4 + 2] = -__expf(a.z);
        Aes[j * 4 + 3] = -__expf(a.w);
    }
    __syncthreads();
    float h[16];
#pragma unroll
    for (int s = 0; s < 16; s++) h[s] = 0.f;
    float cum = 0.f;
    const short* dp = deltab + (size_t)(b * N_ + c * CH_) * E_ + e;
    const short* up = ucb + (size_t)(b * N_ + c * CH_) * E_ + e;
#pragma unroll 2
    for (int n = 0; n < CH_; n++) {
        float dv = bf2f(dp[n * E_]);
        float uv = bf2f(up[n * E_]);
        float du = dv * uv;
        cum += dv;
        float Bl[16];
#pragma unroll
        for (int j = 0; j < 4; j++) *(float4*)&Bl[j * 4] = *(const float4*)&Bsl[n][j * 4];
#pragma unroll
        for (int s = 0; s < 16; s++) {
            float dA = __expf(dv * Aes[s]);
            h[s] = fmaf(dA, h[s], du * Bl[s]);
        }
    }
    size_t ob = (size_t)(b * NC_ + c) * 16 * E_ + e;
#pragma unroll
    for (int s = 0; s < 16; s++) hend[ob + (size_t)s * E_] = h[s];
    cumd[(size_t)(b * NC_ + c) * E_ + e] = cum;
}

__global__ __launch_bounds__(256) void scan_comb(float* __restrict__ hend,
                                                 const float* __restrict__ cumd,
                                                 const float* __restrict__ A_log) {
    int idx = blockIdx.x * 256 + threadIdx.x;   // over B*S*E = 32768
    int b = idx >> 14;
    int s = (idx >> 10) & 15;
    int e = idx & 1023;
    float Aes = -__expf(A_log[e * 16 + s]);
    float h = 0.f;
#pragma unroll 4
    for (int c = 0; c < NC_; c++) {
        size_t i = ((size_t)((b * NC_ + c) * 16) + s) * E_ + e;
        float he = hend[i];
        float P = __expf(Aes * cumd[(size_t)(b * NC_ + c) * E_ + e]);
        hend[i] = h;
        h = fmaf(P, h, he);
    }
}

__global__ __launch_bounds__(256) void scan_p3(const short* __restrict__ deltab,
                                               const short* __restrict__ ucb,
                                               const float* __restrict__ xdbl,
                                               const short* __restrict__ xzb,
                                               const float* __restrict__ A_log,
                                               const float* __restrict__ D_skip,
                                               const float* __restrict__ hend,
                                               short* __restrict__ yb) {
    int blk = blockIdx.x;
    int eq = blk & 3;
    int c = (blk >> 2) & (NC_ - 1);
    int b = blk >> 8;
    int tid = threadIdx.x;
    int e = eq * 256 + tid;
    __shared__ float Bsl[CH_][16];
    __shared__ float Csl[CH_][16];
    int base = (b * N_ + c * CH_) * 64;
    for (int i = tid; i < CH_ * 32; i += 256) {
        int n = i >> 5, col = i & 31;
        float v = xdbl[base + n * 64 + R_ + col];
        if (col < 16) Bsl[n][col] = v;
        else Csl[n][col - 16] = v;
    }
    float Aes[16];
    const float4* al = (const float4*)(A_log + e * 16);
#pragma unroll
    for (int j = 0; j < 4; j++) {
        float4 a = al[j];
        Aes[j * 4 + 0] = -__expf(a.x);
        Aes[j * 4 + 1] = -__expf(a.y);
        Aes[j * 4 + 2] = -__expf(a.z);
        Aes[j * 4 + 3] = -__expf(a.w);
    }
    float dsk = D_skip[e];
    float h[16];
    size_t ob = (size_t)(b * NC_ + c) * 16 * E_ + e;
#pragma unroll
    for (int s = 0; s < 16; s++) h[s] = hend[ob + (size_t)s * E_];
    __syncthreads();
    const short* dp = deltab + (size_t)(b * N_ + c * CH_) * E_ + e;
    const short* up = ucb + (size_t)(b * N_ + c * CH_) * E_ + e;
    const short* zp = xzb + (size_t)(b * N_ + c * CH_) * (2 * E_) + E_ + e;
    short* yp = yb + (size_t)(b * N_ + c * CH_) * E_ + e;
#pragma unroll 2
    for (int n = 0; n < CH_; n++) {
        float dv = bf2f(dp[n * E_]);
        float uv = bf2f(up[n * E_]);
        float du = dv * uv;
        float Bl[16], Cl[16];
#pragma unroll
        for (int j = 0; j < 4; j++) {
            *(float4*)&Bl[j * 4] = *(const float4*)&Bsl[n][j * 4];
            *(float4*)&Cl[j * 4] = *(const float4*)&Csl[n][j * 4];
        }
        float y = 0.f;
#pragma unroll
        for (int s = 0; s < 16; s++) {
            float dA = __expf(dv * Aes[s]);
            h[s] = fmaf(dA, h[s], du * Bl[s]);
            y = fmaf(h[s], Cl[s], y);
        }
        float zv = bf2f(zp[n * 2 * E_]);
        float yy = y + dsk * uv;
        yy = yy * (zv / (1.f + __expf(-zv)));
        yp[n * E_] = f2bf(yy);
    }
}

extern "C" void kernel_launch(void* const* d_in, const int* in_sizes, int n_in,
                              void* d_out, int out_size, void* d_ws, size_t ws_size,
                              hipStream_t stream) {
    const float* x       = (const float*)d_in[0];
    const float* cond    = (const float*)d_in[1];
    const float* ln_g    = (const float*)d_in[2];
    const float* ln_b    = (const float*)d_in[3];
    const float* W_in    = (const float*)d_in[4];
    const float* conv_w  = (const float*)d_in[5];
    const float* conv_b  = (const float*)d_in[6];
    const float* W_x     = (const float*)d_in[7];
    const float* W_dt    = (const float*)d_in[8];
    const float* b_dt    = (const float*)d_in[9];
    const float* A_log   = (const float*)d_in[10];
    const float* D_skip  = (const float*)d_in[11];
    const float* W_out   = (const float*)d_in[12];
    const float* film_gw = (const float*)d_in[13];
    const float* film_gb = (const float*)d_in[14];
    const float* film_bw = (const float*)d_in[15];
    const float* film_bb = (const float*)d_in[16];
    float* out = (float*)d_out;

    float* ws = (float*)d_ws;
    float* xdbl  = ws;                       //   262,144 f
    float* gamma = xdbl + 262144;            //     1,024 f
    float* beta  = gamma + 1024;             //     1,024 f
    float2* stats = (float2*)(beta + 1024);  //     4,096 f2
    float* hend  = (float*)(stats + 4096);   // 2,097,152 f  (B*NC*S*E)
    float* cumd  = hend + 2097152;           //   131,072 f  (B*NC*E)
    short* xzb   = (short*)(cumd + 131072);  // 8,388,608 sh (bf16 xz)
    short* ucb   = xzb + 8388608;            // 4,194,304 sh (bf16 uc)
    short* deltab = ucb + 4194304;           // 4,194,304 sh (bf16 delta)
    short* Wint  = deltab + 4194304;         // 1,048,576 sh
    short* Woutt = Wint + 1048576;           //   524,288 sh
    short* yb    = Woutt + 524288;           // 4,194,304 sh
    short* Wxt   = yb + 4194304;             //    65,536 sh
    short* Wdtt  = Wxt + 65536;              //    32,768 sh

    // prep: film2 + 4 weight transposes + ln_stats, one launch (5736 blocks)
    prep_kernel<<<5736, 256, 0, stream>>>(
        x, stats, W_in, Wint, W_out, Woutt, W_x, Wxt, W_dt, Wdtt,
        cond, film_gw, film_gb, film_bw, film_bb, gamma, beta);

    // xz = LN(x) @ W_in   [4096,512]x[512,2048], LN fused, bf16 output
    gemm_bf16<128, 128, false, true, true>
        <<<dim3(2 * E_ / 128, B_ * N_ / 128), 256, 0, stream>>>(
            x, Wint, xzb, B_ * N_, 2 * E_, D_, stats, ln_g, ln_b, nullptr, nullptr);

    // conv+silu -> xproj -> dt, fused; 256 blocks x 8 waves, 16 tokens each
    mid_kernel<<<B_ * N_ / 16, 512, 0, stream>>>(
        xzb, conv_w, conv_b, Wxt, Wdtt, b_dt, ucb, xdbl, deltab);

    scan_p1<<<B_ * NC_ * 4, 256, 0, stream>>>(deltab, ucb, xdbl, A_log, hend, cumd);
    scan_comb<<<(B_ * S_ * E_) / 256, 256, 0, stream>>>(hend, cumd, A_log);
    scan_p3<<<B_ * NC_ * 4, 256, 0, stream>>>(deltab, ucb, xdbl, xzb, A_log, D_skip, hend, yb);

    // out = FiLM(y @ W_out)   [4096,1024]x[1024,512], fp32 output
    gemm_bf16<128, 64, true, false, false>
        <<<dim3(D_ / 64, B_ * N_ / 128), 256, 0, stream>>>(
            yb, Woutt, out, B_ * N_, D_, E_, nullptr, nullptr, nullptr, gamma, beta);
}

// Round 12
// 144.730 us; speedup vs baseline: 4.0887x; 1.0452x over previous
//
#include <hip/hip_runtime.h>
#include <hip/hip_bf16.h>
#include <math.h>

#define B_ 2
#define N_ 2048
#define D_ 512
#define E_ 1024
#define S_ 16
#define R_ 32
#define C_ 512
#define CH_ 32
#define NC_ (N_ / CH_)   // 64 chunks

using short8 = __attribute__((ext_vector_type(8))) short;
using f32x4  = __attribute__((ext_vector_type(4))) float;
using f32x16 = __attribute__((ext_vector_type(16))) float;

__device__ __forceinline__ short f2bf(float f) {
    union { float f; unsigned u; } x; x.f = f;
    unsigned r = (x.u + 0x7fffu + ((x.u >> 16) & 1u)) >> 16;
    return (short)r;
}
__device__ __forceinline__ float bf2f(short s) {
    union { unsigned u; float f; } x;
    x.u = ((unsigned)(unsigned short)s) << 16;
    return x.f;
}
// wave-level async global->LDS, 16B per lane (lds dest wave-uniform base + lane*16)
__device__ __forceinline__ void gl_lds16(const void* g, void* l) {
    __builtin_amdgcn_global_load_lds((const __attribute__((address_space(1))) void*)g,
                                     (__attribute__((address_space(3))) void*)l, 16, 0, 0);
}

// ================= prep: film2 | 4 transposes | ln_stats, one launch =================
__global__ __launch_bounds__(256) void prep_kernel(
    const float* __restrict__ x, float2* __restrict__ stats,
    const float* __restrict__ W_in, short* __restrict__ Wint,
    const float* __restrict__ W_out, short* __restrict__ Woutt,
    const float* __restrict__ W_x, short* __restrict__ Wxt,
    const float* __restrict__ W_dt, short* __restrict__ Wdtt,
    const float* __restrict__ cond,
    const float* __restrict__ gw, const float* __restrict__ gb,
    const float* __restrict__ bw, const float* __restrict__ bb,
    float* __restrict__ gamma, float* __restrict__ beta) {
    __shared__ __align__(16) float smem[2112];
    int bid = blockIdx.x;
    int tid = threadIdx.x;
    if (bid < 8) {
        float* cs = smem;            // [2][512]
        float* red = smem + 1024;    // [4][64][4]
        int d0 = bid * 64;
#pragma unroll
        for (int i = tid; i < 2 * C_ / 4; i += 256) {
            int b = i >> 7;
            int c4 = (i & 127) * 4;
            *(float4*)&cs[b * C_ + c4] = *(const float4*)(cond + (size_t)b * C_ + c4);
        }
        __syncthreads();
        int dl = tid & 63, ks = tid >> 6;
        int d = d0 + dl;
        float g0 = 0.f, g1 = 0.f, bt0 = 0.f, bt1 = 0.f;
#pragma unroll 4
        for (int k = ks * 128; k < ks * 128 + 128; k++) {
            float wg = gw[(size_t)k * D_ + d];
            float wb = bw[(size_t)k * D_ + d];
            float c0 = cs[k], c1 = cs[C_ + k];
            g0 = fmaf(c0, wg, g0);
            g1 = fmaf(c1, wg, g1);
            bt0 = fmaf(c0, wb, bt0);
            bt1 = fmaf(c1, wb, bt1);
        }
        red[(ks * 64 + dl) * 4 + 0] = g0; red[(ks * 64 + dl) * 4 + 1] = g1;
        red[(ks * 64 + dl) * 4 + 2] = bt0; red[(ks * 64 + dl) * 4 + 3] = bt1;
        __syncthreads();
        if (ks == 0) {
            float s0 = 0.f, s1 = 0.f, s2 = 0.f, s3 = 0.f;
#pragma unroll
            for (int q = 0; q < 4; q++) {
                s0 += red[(q * 64 + dl) * 4 + 0]; s1 += red[(q * 64 + dl) * 4 + 1];
                s2 += red[(q * 64 + dl) * 4 + 2]; s3 += red[(q * 64 + dl) * 4 + 3];
            }
            float gbv = gb[d], bbv = bb[d];
            gamma[d] = s0 + gbv;
            gamma[D_ + d] = s1 + gbv;
            beta[d] = s2 + bbv;
            beta[D_ + d] = s3 + bbv;
        }
    } else if (bid < 1640) {
        const float* W; short* Wt; int K, N, bx, by;
        int r = bid - 8;
        if (r < 1024)      { W = W_in;  Wt = Wint;  K = 512;  N = 2048; bx = r % 64; by = r / 64; }
        else if (r < 1536) { r -= 1024; W = W_out; Wt = Woutt; K = 1024; N = 512; bx = r % 16; by = r / 16; }
        else if (r < 1600) { r -= 1536; W = W_x;   Wt = Wxt;   K = 1024; N = 64;  bx = r % 2;  by = r / 2; }
        else               { r -= 1600; W = W_dt;  Wt = Wdtt;  K = 32;   N = 1024; bx = r;     by = 0; }
        float (*t)[33] = (float(*)[33])smem;
        int n0 = bx * 32, k0 = by * 32;
        int c = tid & 31, rr0 = tid >> 5;
#pragma unroll
        for (int rr = rr0; rr < 32; rr += 8)
            t[rr][c] = W[(size_t)(k0 + rr) * N + n0 + c];
        __syncthreads();
#pragma unroll
        for (int rr = rr0; rr < 32; rr += 8)
            Wt[(size_t)(n0 + rr) * K + k0 + c] = f2bf(t[c][rr]);
    } else {
        int t = bid - 1640;
        float2 v = *(const float2*)(x + (size_t)t * D_ + tid * 2);
        float s = v.x + v.y;
        float s2 = fmaf(v.x, v.x, v.y * v.y);
#pragma unroll
        for (int o = 32; o >= 1; o >>= 1) {
            s += __shfl_down(s, o);
            s2 += __shfl_down(s2, o);
        }
        int wid = tid >> 6;
        if ((tid & 63) == 0) { smem[wid] = s; smem[4 + wid] = s2; }
        __syncthreads();
        if (tid == 0) {
            float sum = smem[0] + smem[1] + smem[2] + smem[3];
            float sum2 = smem[4] + smem[5] + smem[6] + smem[7];
            float mu = sum * (1.f / (float)D_);
            float var = sum2 * (1.f / (float)D_) - mu * mu;
            stats[t] = make_float2(mu, rsqrtf(var + 1e-5f));
        }
    }
}

// ---------------- bf16 MFMA GEMM: C[M][N] = A[M][K] * Bt[N][K]^T ----------------
// 1-D grid, XCD-swizzled tile decode. LNA: A fp32 + LN in staging (reg-staged,
// padded LDS). Pure-copy operands use global_load_lds w16 into linear LDS.
template <int BM, int BN, bool FILM, bool LNA, bool OBF>
__global__ __launch_bounds__(256) void gemm_bf16(
    const void* __restrict__ Av, const short* __restrict__ Bt, void* __restrict__ Cv,
    int M, int N, int K,
    const float2* __restrict__ stats, const float* __restrict__ lng, const float* __restrict__ lnb,
    const float* __restrict__ gamma, const float* __restrict__ beta) {
    constexpr int BK = 64;
    constexpr int LDA = LNA ? 72 : 64;   // padded only when reg-staged
    constexpr int LDB = 64;              // linear: required by global_load_lds
    constexpr int WM = BM / 2, WN = BN / 2;
    constexpr int MR = WM / 32, NR = WN / 32;
    __shared__ __align__(16) short As[BM * LDA];
    __shared__ __align__(16) short Bs[BN * LDB];
    int tid = threadIdx.x;
    int lane = tid & 63, w = tid >> 6;
    int wr = w >> 1, wc = w & 1;
    // XCD-aware swizzle: each XCD gets a contiguous chunk of tile-space (T1)
    int lid = blockIdx.x;
    int chunk = gridDim.x >> 3;
    int swz = (lid & 7) * chunk + (lid >> 3);
    int ntiles = N / BN;
    int m0 = (swz / ntiles) * BM, n0 = (swz % ntiles) * BN;
    int lr = lane >> 3, lc = lane & 7;   // gload_lds: lane -> (row-in-chunk, 16B-col)

    f32x16 acc[MR][NR];
#pragma unroll
    for (int i = 0; i < MR; i++)
#pragma unroll
        for (int j = 0; j < NR; j++)
#pragma unroll
            for (int r = 0; r < 16; r++) acc[i][j][r] = 0.f;

    int l31 = lane & 31, hk = (lane >> 5) * 8;

    for (int k0 = 0; k0 < K; k0 += BK) {
        __syncthreads();
        if constexpr (LNA) {
            const float* Af = (const float*)Av;
#pragma unroll
            for (int i = tid; i < BM * 8; i += 256) {
                int r = i >> 3, c = (i & 7) * 8;
                float2 st = stats[m0 + r];
                const float* src = Af + (size_t)(m0 + r) * K + k0 + c;
                float4 v0 = *(const float4*)src;
                float4 v1 = *(const float4*)(src + 4);
                float4 g0 = *(const float4*)(lng + k0 + c);
                float4 g1 = *(const float4*)(lng + k0 + c + 4);
                float4 b0 = *(const float4*)(lnb + k0 + c);
                float4 b1 = *(const float4*)(lnb + k0 + c + 4);
                short8 o;
                o[0] = f2bf((v0.x - st.x) * st.y * g0.x + b0.x);
                o[1] = f2bf((v0.y - st.x) * st.y * g0.y + b0.y);
                o[2] = f2bf((v0.z - st.x) * st.y * g0.z + b0.z);
                o[3] = f2bf((v0.w - st.x) * st.y * g0.w + b0.w);
                o[4] = f2bf((v1.x - st.x) * st.y * g1.x + b1.x);
                o[5] = f2bf((v1.y - st.x) * st.y * g1.y + b1.y);
                o[6] = f2bf((v1.z - st.x) * st.y * g1.z + b1.z);
                o[7] = f2bf((v1.w - st.x) * st.y * g1.w + b1.w);
                *(short8*)&As[r * LDA + c] = o;
            }
        } else {
            const short* Ab = (const short*)Av;
#pragma unroll
            for (int ch = w; ch < BM / 8; ch += 4)
                gl_lds16(&Ab[(size_t)(m0 + ch * 8 + lr) * K + k0 + lc * 8], &As[ch * 512]);
        }
#pragma unroll
        for (int ch = w; ch < BN / 8; ch += 4)
            gl_lds16(&Bt[(size_t)(n0 + ch * 8 + lr) * K + k0 + lc * 8], &Bs[ch * 512]);
        __syncthreads();   // drains vmcnt (gload_lds) + lgkmcnt (ds_write)
#pragma unroll
        for (int kk = 0; kk < 4; kk++) {
            short8 a[MR], b[NR];
#pragma unroll
            for (int i = 0; i < MR; i++)
                a[i] = *(const short8*)&As[(wr * WM + i * 32 + l31) * LDA + kk * 16 + hk];
#pragma unroll
            for (int j = 0; j < NR; j++)
                b[j] = *(const short8*)&Bs[(wc * WN + j * 32 + l31) * LDB + kk * 16 + hk];
#pragma unroll
            for (int i = 0; i < MR; i++)
#pragma unroll
                for (int j = 0; j < NR; j++)
                    acc[i][j] = __builtin_amdgcn_mfma_f32_32x32x16_bf16(a[i], b[j], acc[i][j], 0, 0, 0);
        }
    }
    int rbase = 4 * (lane >> 5);
    int bi = m0 >> 11;   // batch index
#pragma unroll
    for (int i = 0; i < MR; i++)
#pragma unroll
        for (int j = 0; j < NR; j++) {
            int col = n0 + wc * WN + j * 32 + l31;
            float gm = 1.f, bt = 0.f;
            if (FILM) {
                gm = gamma[bi * D_ + col];
                bt = beta[bi * D_ + col];
            }
#pragma unroll
            for (int r = 0; r < 16; r++) {
                int row = m0 + wr * WM + i * 32 + rbase + (r & 3) + 8 * (r >> 2);
                float v = acc[i][j][r];
                if (FILM) v = gm * v + bt;
                if constexpr (OBF)
                    ((short*)Cv)[(size_t)row * N + col] = f2bf(v);
                else
                    ((float*)Cv)[(size_t)row * N + col] = v;
            }
        }
}

// ================= mid: sliding-window conv -> xproj -> dt; 16 tok/block, 8 waves =================
__global__ __launch_bounds__(512) void mid_kernel(
    const short* __restrict__ xzb, const float* __restrict__ cw, const float* __restrict__ cb,
    const short* __restrict__ Wxt,   // [64][1024] bf16
    const short* __restrict__ Wdtt,  // [1024][32] bf16
    const float* __restrict__ bdt,
    short* __restrict__ ucb, float* __restrict__ xdbl, short* __restrict__ deltab) {
    constexpr int LDU = 1032;                        // 2064B pitch
    __shared__ __align__(16) short u[16 * LDU];      // 33 KB uc (bf16)
    __shared__ __align__(16) float xd2[2][16 * 68];  // 8.7 KB x_dbl partials
    int tid = threadIdx.x;
    int t0 = blockIdx.x * 16;
    int n0 = t0 & (N_ - 1);
    // ---- conv+SiLU: thread -> 8-wide e-chunk, 4 tokens; 7-row sliding window ----
    {
        int c8 = (tid & 127) * 8;      // e offset
        int base = (tid >> 7) * 4;     // first token of this thread's group
        float4 wv[8];
        float cbv[8];
#pragma unroll
        for (int j = 0; j < 8; j++) {
            wv[j] = *(const float4*)(cw + (c8 + j) * 4);
            cbv[j] = cb[c8 + j];
        }
        float uf[7][8];
#pragma unroll
        for (int j = 0; j < 7; j++) {
            short8 v = {0, 0, 0, 0, 0, 0, 0, 0};
            if (n0 + base - 3 + j >= 0)
                v = *(const short8*)&xzb[(size_t)(t0 + base - 3 + j) * (2 * E_) + c8];
#pragma unroll
            for (int q = 0; q < 8; q++) uf[j][q] = bf2f(v[q]);
        }
#pragma unroll
        for (int k = 0; k < 4; k++) {
            int n = base + k;
            short8 o;
#pragma unroll
            for (int q = 0; q < 8; q++) {
                float a = fmaf(wv[q].x, uf[k][q],
                          fmaf(wv[q].y, uf[k + 1][q],
                          fmaf(wv[q].z, uf[k + 2][q],
                          fmaf(wv[q].w, uf[k + 3][q], cbv[q]))));
                float v = a / (1.f + __expf(-a));
                o[q] = f2bf(v);
            }
            *(short8*)&ucb[(size_t)(t0 + n) * E_ + c8] = o;
            *(short8*)&u[n * LDU + c8] = o;
        }
    }
    __syncthreads();
    // ---- xproj: 8 waves; wave w -> cols [cg*16,+16), K-half kh; partials in xd2[kh] ----
    int lane = tid & 63, w = tid >> 6;
    int cg = w & 3, kh = w >> 2;
    int l15 = lane & 15, kq = (lane >> 4) * 8;
    f32x4 acc4 = {0.f, 0.f, 0.f, 0.f};
#pragma unroll 8
    for (int k0 = 0; k0 < 16; k0++) {
        int kk = kh * 512 + k0 * 32;
        short8 af = *(const short8*)&u[l15 * LDU + kk + kq];
        short8 bfr = *(const short8*)&Wxt[(size_t)(cg * 16 + l15) * E_ + kk + kq];
        acc4 = __builtin_amdgcn_mfma_f32_16x16x32_bf16(af, bfr, acc4, 0, 0, 0);
    }
#pragma unroll
    for (int j = 0; j < 4; j++)
        xd2[kh][((lane >> 4) * 4 + j) * 68 + cg * 16 + l15] = acc4[j];
    __syncthreads();
    // reduce K-halves, write x_dbl, keep sum in xd2[0]
    if (tid < 256) {
        int r = tid >> 4, c4 = (tid & 15) * 4;
        float4 a = *(const float4*)&xd2[0][r * 68 + c4];
        float4 b = *(const float4*)&xd2[1][r * 68 + c4];
        a.x += b.x; a.y += b.y; a.z += b.z; a.w += b.w;
        *(float4*)&xd2[0][r * 68 + c4] = a;
        *(float4*)&xdbl[(size_t)(t0 + r) * 64 + c4] = a;
    }
    __syncthreads();
    // ---- dt: 8 waves x 8 e-tiles of 16 ----
    float av[8];
    *(float4*)&av[0] = *(const float4*)&xd2[0][l15 * 68 + kq];
    *(float4*)&av[4] = *(const float4*)&xd2[0][l15 * 68 + kq + 4];
    short8 ab;
#pragma unroll
    for (int j = 0; j < 8; j++) ab[j] = f2bf(av[j]);
    int row4 = (lane >> 4) * 4;
#pragma unroll 4
    for (int t = 0; t < 8; t++) {
        int e = w * 128 + t * 16 + l15;
        short8 bb = *(const short8*)&Wdtt[(size_t)e * 32 + kq];
        f32x4 c4v = {0.f, 0.f, 0.f, 0.f};
        c4v = __builtin_amdgcn_mfma_f32_16x16x32_bf16(ab, bb, c4v, 0, 0, 0);
        float bv = bdt[e];
#pragma unroll
        for (int j = 0; j < 4; j++) {
            float xv = c4v[j] + bv;
            float sp = (xv > 20.f) ? xv : log1pf(__expf(xv));
            deltab[(size_t)(t0 + row4 + j) * E_ + e] = f2bf(sp);
        }
    }
}

// ---------------- chunked selective scan, s-in-registers (bf16 inputs) ----------------
__global__ __launch_bounds__(256) void scan_p1(const short* __restrict__ deltab,
                                               const short* __restrict__ ucb,
                                               const float* __restrict__ xdbl,
                                               const float* __restrict__ A_log,
                                               float* __restrict__ hend,
                                               float* __restrict__ cumd) {
    int blk = blockIdx.x;            // b*(NC_*4) + c*4 + eq
    int eq = blk & 3;
    int c = (blk >> 2) & (NC_ - 1);
    int b = blk >> 8;
    int tid = threadIdx.x;
    int e = eq * 256 + tid;
    __shared__ float Bsl[CH_][16];
    int base = (b * N_ + c * CH_) * 64;
    for (int i = tid; i < CH_ * 16; i += 256) {
        int n = i >> 4, col = i & 15;
        Bsl[n][col] = xdbl[base + n * 64 + R_ + col];
    }
    float Aes[16];
    const float4* al = (const float4*)(A_log + e * 16);
#pragma unroll
    for (int j = 0; j < 4; j++) {
        float4 a = al[j];
        Aes[j * 4 + 0] = -__expf(a.x);
        Aes[j * 4 + 1] = -__expf(a.y);
        Aes[j * 4 + 2] = -__expf(a.z);
        Aes[j * 4 + 3] = -__expf(a.w);
    }
    __syncthreads();
    float h[16];
#pragma unroll
    for (int s = 0; s < 16; s++) h[s] = 0.f;
    float cum = 0.f;
    const short* dp = deltab + (size_t)(b * N_ + c * CH_) * E_ + e;
    const short* up = ucb + (size_t)(b * N_ + c * CH_) * E_ + e;
#pragma unroll 2
    for (int n = 0; n < CH_; n++) {
        float dv = bf2f(dp[n * E_]);
        float uv = bf2f(up[n * E_]);
        float du = dv * uv;
        cum += dv;
        float Bl[16];
#pragma unroll
        for (int j = 0; j < 4; j++) *(float4*)&Bl[j * 4] = *(const float4*)&Bsl[n][j * 4];
#pragma unroll
        for (int s = 0; s < 16; s++) {
            float dA = __expf(dv * Aes[s]);
            h[s] = fmaf(dA, h[s], du * Bl[s]);
        }
    }
    size_t ob = (size_t)(b * NC_ + c) * 16 * E_ + e;
#pragma unroll
    for (int s = 0; s < 16; s++) hend[ob + (size_t)s * E_] = h[s];
    cumd[(size_t)(b * NC_ + c) * E_ + e] = cum;
}

// ---- comb: wave-parallel Kogge-Stone over chunks; block = (b, s, 64-e tile) ----
// transforms hend in place into chunk-entry states (exclusive scan of (P,hend))
__global__ __launch_bounds__(256) void scan_comb(float* __restrict__ hend,
                                                 const float* __restrict__ cumd,
                                                 const float* __restrict__ A_log) {
    __shared__ float lh[64][65];   // [c][e]
    __shared__ float lp[64][65];
    int blk = blockIdx.x;          // b*256 + s*16 + et
    int et = blk & 15;
    int s = (blk >> 4) & 15;
    int b = blk >> 8;
    int e0 = et * 64;
    int tid = threadIdx.x;
    int lane = tid & 63, w = tid >> 6;
    // coalesced load: hend[b][c][s][e0..e0+63], cumd[b][c][e0..e0+63]
    for (int i = tid; i < 64 * 64; i += 256) {
        int c = i >> 6, e = i & 63;
        lh[c][e] = hend[((size_t)((b * NC_ + c) * 16) + s) * E_ + e0 + e];
        lp[c][e] = cumd[(size_t)(b * NC_ + c) * E_ + e0 + e];
    }
    __syncthreads();
    // wave w handles chains e = w*16 .. w*16+15; lane = chunk c
#pragma unroll 4
    for (int q = 0; q < 16; q++) {
        int e = w * 16 + q;
        float Aes = -__expf(A_log[(e0 + e) * 16 + s]);
        float A = __expf(Aes * lp[lane][e]);
        float Bv = lh[lane][e];
#pragma unroll
        for (int off = 1; off < 64; off <<= 1) {
            float Ap = __shfl_up(A, off);
            float Bp = __shfl_up(Bv, off);
            if (lane >= off) {
                Bv = fmaf(A, Bp, Bv);
                A *= Ap;
            }
        }
        float hB = __shfl_up(Bv, 1);
        lh[lane][e] = (lane == 0) ? 0.f : hB;   // exclusive scan result
    }
    __syncthreads();
    // coalesced store back
    for (int i = tid; i < 64 * 64; i += 256) {
        int c = i >> 6, e = i & 63;
        hend[((size_t)((b * NC_ + c) * 16) + s) * E_ + e0 + e] = lh[c][e];
    }
}

__global__ __launch_bounds__(256) void scan_p3(const short* __restrict__ deltab,
                                               const short* __restrict__ ucb,
                                               const float* __restrict__ xdbl,
                                               const short* __restrict__ xzb,
                                               const float* __restrict__ A_log,
                                               const float* __restrict__ D_skip,
                                               const float* __restrict__ hend,
                                               short* __restrict__ yb) {
    int blk = blockIdx.x;
    int eq = blk & 3;
    int c = (blk >> 2) & (NC_ - 1);
    int b = blk >> 8;
    int tid = threadIdx.x;
    int e = eq * 256 + tid;
    __shared__ float Bsl[CH_][16];
    __shared__ float Csl[CH_][16];
    int base = (b * N_ + c * CH_) * 64;
    for (int i = tid; i < CH_ * 32; i += 256) {
        int n = i >> 5, col = i & 31;
        float v = xdbl[base + n * 64 + R_ + col];
        if (col < 16) Bsl[n][col] = v;
        else Csl[n][col - 16] = v;
    }
    float Aes[16];
    const float4* al = (const float4*)(A_log + e * 16);
#pragma unroll
    for (int j = 0; j < 4; j++) {
        float4 a = al[j];
        Aes[j * 4 + 0] = -__expf(a.x);
        Aes[j * 4 + 1] = -__expf(a.y);
        Aes[j * 4 + 2] = -__expf(a.z);
        Aes[j * 4 + 3] = -__expf(a.w);
    }
    float dsk = D_skip[e];
    float h[16];
    size_t ob = (size_t)(b * NC_ + c) * 16 * E_ + e;
#pragma unroll
    for (int s = 0; s < 16; s++) h[s] = hend[ob + (size_t)s * E_];
    __syncthreads();
    const short* dp = deltab + (size_t)(b * N_ + c * CH_) * E_ + e;
    const short* up = ucb + (size_t)(b * N_ + c * CH_) * E_ + e;
    const short* zp = xzb + (size_t)(b * N_ + c * CH_) * (2 * E_) + E_ + e;
    short* yp = yb + (size_t)(b * N_ + c * CH_) * E_ + e;
#pragma unroll 2
    for (int n = 0; n < CH_; n++) {
        float dv = bf2f(dp[n * E_]);
        float uv = bf2f(up[n * E_]);
        float du = dv * uv;
        float Bl[16], Cl[16];
#pragma unroll
        for (int j = 0; j < 4; j++) {
            *(float4*)&Bl[j * 4] = *(const float4*)&Bsl[n][j * 4];
            *(float4*)&Cl[j * 4] = *(const float4*)&Csl[n][j * 4];
        }
        float y = 0.f;
#pragma unroll
        for (int s = 0; s < 16; s++) {
            float dA = __expf(dv * Aes[s]);
            h[s] = fmaf(dA, h[s], du * Bl[s]);
            y = fmaf(h[s], Cl[s], y);
        }
        float zv = bf2f(zp[n * 2 * E_]);
        float yy = y + dsk * uv;
        yy = yy * (zv / (1.f + __expf(-zv)));
        yp[n * E_] = f2bf(yy);
    }
}

extern "C" void kernel_launch(void* const* d_in, const int* in_sizes, int n_in,
                              void* d_out, int out_size, void* d_ws, size_t ws_size,
                              hipStream_t stream) {
    const float* x       = (const float*)d_in[0];
    const float* cond    = (const float*)d_in[1];
    const float* ln_g    = (const float*)d_in[2];
    const float* ln_b    = (const float*)d_in[3];
    const float* W_in    = (const float*)d_in[4];
    const float* conv_w  = (const float*)d_in[5];
    const float* conv_b  = (const float*)d_in[6];
    const float* W_x     = (const float*)d_in[7];
    const float* W_dt    = (const float*)d_in[8];
    const float* b_dt    = (const float*)d_in[9];
    const float* A_log   = (const float*)d_in[10];
    const float* D_skip  = (const float*)d_in[11];
    const float* W_out   = (const float*)d_in[12];
    const float* film_gw = (const float*)d_in[13];
    const float* film_gb = (const float*)d_in[14];
    const float* film_bw = (const float*)d_in[15];
    const float* film_bb = (const float*)d_in[16];
    float* out = (float*)d_out;

    float* ws = (float*)d_ws;
    float* xdbl  = ws;                       //   262,144 f
    float* gamma = xdbl + 262144;            //     1,024 f
    float* beta  = gamma + 1024;             //     1,024 f
    float2* stats = (float2*)(beta + 1024);  //     4,096 f2
    float* hend  = (float*)(stats + 4096);   // 2,097,152 f  (B*NC*S*E)
    float* cumd  = hend + 2097152;           //   131,072 f  (B*NC*E)
    short* xzb   = (short*)(cumd + 131072);  // 8,388,608 sh (bf16 xz)
    short* ucb   = xzb + 8388608;            // 4,194,304 sh (bf16 uc)
    short* deltab = ucb + 4194304;           // 4,194,304 sh (bf16 delta)
    short* Wint  = deltab + 4194304;         // 1,048,576 sh
    short* Woutt = Wint + 1048576;           //   524,288 sh
    short* yb    = Woutt + 524288;           // 4,194,304 sh
    short* Wxt   = yb + 4194304;             //    65,536 sh
    short* Wdtt  = Wxt + 65536;              //    32,768 sh

    // prep: film2 + 4 weight transposes + ln_stats, one launch (5736 blocks)
    prep_kernel<<<5736, 256, 0, stream>>>(
        x, stats, W_in, Wint, W_out, Woutt, W_x, Wxt, W_dt, Wdtt,
        cond, film_gw, film_gb, film_bw, film_bb, gamma, beta);

    // xz = LN(x) @ W_in   [4096,512]x[512,2048], LN fused, bf16 output, XCD-swizzled
    gemm_bf16<128, 128, false, true, true>
        <<<512, 256, 0, stream>>>(
            x, Wint, xzb, B_ * N_, 2 * E_, D_, stats, ln_g, ln_b, nullptr, nullptr);

    // conv+silu -> xproj -> dt, fused; 256 blocks x 8 waves, 16 tokens each
    mid_kernel<<<B_ * N_ / 16, 512, 0, stream>>>(
        xzb, conv_w, conv_b, Wxt, Wdtt, b_dt, ucb, xdbl, deltab);

    scan_p1<<<B_ * NC_ * 4, 256, 0, stream>>>(deltab, ucb, xdbl, A_log, hend, cumd);
    scan_comb<<<B_ * S_ * (E_ / 64), 256, 0, stream>>>(hend, cumd, A_log);
    scan_p3<<<B_ * NC_ * 4, 256, 0, stream>>>(deltab, ucb, xdbl, xzb, A_log, D_skip, hend, yb);

    // out = FiLM(y @ W_out)   [4096,1024]x[1024,512], fp32 output, XCD-swizzled
    gemm_bf16<128, 64, true, false, false>
        <<<256, 256, 0, stream>>>(
            yb, Woutt, out, B_ * N_, D_, E_, nullptr, nullptr, nullptr, gamma, beta);
}

// Round 13
// 136.828 us; speedup vs baseline: 4.3248x; 1.0578x over previous
//
#include <hip/hip_runtime.h>
#include <hip/hip_bf16.h>
#include <math.h>

#define B_ 2
#define N_ 2048
#define D_ 512
#define E_ 1024
#define S_ 16
#define R_ 32
#define C_ 512
#define CH_ 32
#define NC_ (N_ / CH_)   // 64 chunks

using short8 = __attribute__((ext_vector_type(8))) short;
using f32x4  = __attribute__((ext_vector_type(4))) float;
using f32x16 = __attribute__((ext_vector_type(16))) float;

__device__ __forceinline__ short f2bf(float f) {
    union { float f; unsigned u; } x; x.f = f;
    unsigned r = (x.u + 0x7fffu + ((x.u >> 16) & 1u)) >> 16;
    return (short)r;
}
__device__ __forceinline__ float bf2f(short s) {
    union { unsigned u; float f; } x;
    x.u = ((unsigned)(unsigned short)s) << 16;
    return x.f;
}
// wave-level async global->LDS, 16B per lane (lds dest wave-uniform base + lane*16)
__device__ __forceinline__ void gl_lds16(const void* g, void* l) {
    __builtin_amdgcn_global_load_lds((const __attribute__((address_space(1))) void*)g,
                                     (__attribute__((address_space(3))) void*)l, 16, 0, 0);
}

// ================= prep: film2 | 4 transposes | LN stats+apply (bf16 xn), one launch =================
__global__ __launch_bounds__(256) void prep_kernel(
    const float* __restrict__ x, short* __restrict__ xnb,
    const float* __restrict__ W_in, short* __restrict__ Wint,
    const float* __restrict__ W_out, short* __restrict__ Woutt,
    const float* __restrict__ W_x, short* __restrict__ Wxt,
    const float* __restrict__ W_dt, short* __restrict__ Wdtt,
    const float* __restrict__ cond,
    const float* __restrict__ lng, const float* __restrict__ lnb,
    const float* __restrict__ gw, const float* __restrict__ gb,
    const float* __restrict__ bw, const float* __restrict__ bb,
    float* __restrict__ gamma, float* __restrict__ beta) {
    __shared__ __align__(16) float smem[2112];
    int bid = blockIdx.x;
    int tid = threadIdx.x;
    if (bid < 8) {
        float* cs = smem;            // [2][512]
        float* red = smem + 1024;    // [4][64][4]
        int d0 = bid * 64;
#pragma unroll
        for (int i = tid; i < 2 * C_ / 4; i += 256) {
            int b = i >> 7;
            int c4 = (i & 127) * 4;
            *(float4*)&cs[b * C_ + c4] = *(const float4*)(cond + (size_t)b * C_ + c4);
        }
        __syncthreads();
        int dl = tid & 63, ks = tid >> 6;
        int d = d0 + dl;
        float g0 = 0.f, g1 = 0.f, bt0 = 0.f, bt1 = 0.f;
#pragma unroll 4
        for (int k = ks * 128; k < ks * 128 + 128; k++) {
            float wg = gw[(size_t)k * D_ + d];
            float wb = bw[(size_t)k * D_ + d];
            float c0 = cs[k], c1 = cs[C_ + k];
            g0 = fmaf(c0, wg, g0);
            g1 = fmaf(c1, wg, g1);
            bt0 = fmaf(c0, wb, bt0);
            bt1 = fmaf(c1, wb, bt1);
        }
        red[(ks * 64 + dl) * 4 + 0] = g0; red[(ks * 64 + dl) * 4 + 1] = g1;
        red[(ks * 64 + dl) * 4 + 2] = bt0; red[(ks * 64 + dl) * 4 + 3] = bt1;
        __syncthreads();
        if (ks == 0) {
            float s0 = 0.f, s1 = 0.f, s2 = 0.f, s3 = 0.f;
#pragma unroll
            for (int q = 0; q < 4; q++) {
                s0 += red[(q * 64 + dl) * 4 + 0]; s1 += red[(q * 64 + dl) * 4 + 1];
                s2 += red[(q * 64 + dl) * 4 + 2]; s3 += red[(q * 64 + dl) * 4 + 3];
            }
            float gbv = gb[d], bbv = bb[d];
            gamma[d] = s0 + gbv;
            gamma[D_ + d] = s1 + gbv;
            beta[d] = s2 + bbv;
            beta[D_ + d] = s3 + bbv;
        }
    } else if (bid < 1640) {
        const float* W; short* Wt; int K, N, bx, by;
        int r = bid - 8;
        if (r < 1024)      { W = W_in;  Wt = Wint;  K = 512;  N = 2048; bx = r % 64; by = r / 64; }
        else if (r < 1536) { r -= 1024; W = W_out; Wt = Woutt; K = 1024; N = 512; bx = r % 16; by = r / 16; }
        else if (r < 1600) { r -= 1536; W = W_x;   Wt = Wxt;   K = 1024; N = 64;  bx = r % 2;  by = r / 2; }
        else               { r -= 1600; W = W_dt;  Wt = Wdtt;  K = 32;   N = 1024; bx = r;     by = 0; }
        float (*t)[33] = (float(*)[33])smem;
        int n0 = bx * 32, k0 = by * 32;
        int c = tid & 31, rr0 = tid >> 5;
#pragma unroll
        for (int rr = rr0; rr < 32; rr += 8)
            t[rr][c] = W[(size_t)(k0 + rr) * N + n0 + c];
        __syncthreads();
#pragma unroll
        for (int rr = rr0; rr < 32; rr += 8)
            Wt[(size_t)(n0 + rr) * K + k0 + c] = f2bf(t[c][rr]);
    } else {
        // ---- LN stats + apply, one token per block; writes bf16 xn ----
        int t = bid - 1640;
        float2 v = *(const float2*)(x + (size_t)t * D_ + tid * 2);
        float s = v.x + v.y;
        float s2 = fmaf(v.x, v.x, v.y * v.y);
#pragma unroll
        for (int o = 32; o >= 1; o >>= 1) {
            s += __shfl_down(s, o);
            s2 += __shfl_down(s2, o);
        }
        int wid = tid >> 6;
        if ((tid & 63) == 0) { smem[wid] = s; smem[4 + wid] = s2; }
        __syncthreads();
        if (tid == 0) {
            float sum = smem[0] + smem[1] + smem[2] + smem[3];
            float sum2 = smem[4] + smem[5] + smem[6] + smem[7];
            float mu = sum * (1.f / (float)D_);
            float var = sum2 * (1.f / (float)D_) - mu * mu;
            smem[8] = mu;
            smem[9] = rsqrtf(var + 1e-5f);
        }
        __syncthreads();
        float mu = smem[8], rs = smem[9];
        float2 gv = *(const float2*)(lng + tid * 2);
        float2 bv = *(const float2*)(lnb + tid * 2);
        short2 o;
        o.x = f2bf((v.x - mu) * rs * gv.x + bv.x);
        o.y = f2bf((v.y - mu) * rs * gv.y + bv.y);
        *(short2*)(xnb + (size_t)t * D_ + tid * 2) = o;
    }
}

// ---------------- bf16 MFMA GEMM: C[M][N] = A[M][K] * Bt[N][K]^T ----------------
// 1-D grid, XCD-swizzled tile decode. Both operands staged via global_load_lds
// width-16 into linear LDS (8 rows x 8 chunks = 64 lanes x 16B per wave-op).
template <int BM, int BN, bool FILM, bool OBF>
__global__ __launch_bounds__(256) void gemm_bf16(
    const short* __restrict__ A, const short* __restrict__ Bt, void* __restrict__ Cv,
    int M, int N, int K,
    const float* __restrict__ gamma, const float* __restrict__ beta) {
    constexpr int BK = 64;
    constexpr int WM = BM / 2, WN = BN / 2;
    constexpr int MR = WM / 32, NR = WN / 32;
    __shared__ __align__(16) short As[BM * BK];
    __shared__ __align__(16) short Bs[BN * BK];
    int tid = threadIdx.x;
    int lane = tid & 63, w = tid >> 6;
    int wr = w >> 1, wc = w & 1;
    // XCD-aware swizzle: each XCD gets a contiguous chunk of tile-space (T1)
    int lid = blockIdx.x;
    int chunk = gridDim.x >> 3;
    int swz = (lid & 7) * chunk + (lid >> 3);
    int ntiles = N / BN;
    int m0 = (swz / ntiles) * BM, n0 = (swz % ntiles) * BN;
    int lr = lane >> 3, lc = lane & 7;   // gload_lds: lane -> (row-in-chunk, 16B-col)

    f32x16 acc[MR][NR];
#pragma unroll
    for (int i = 0; i < MR; i++)
#pragma unroll
        for (int j = 0; j < NR; j++)
#pragma unroll
            for (int r = 0; r < 16; r++) acc[i][j][r] = 0.f;

    int l31 = lane & 31, hk = (lane >> 5) * 8;

    for (int k0 = 0; k0 < K; k0 += BK) {
        __syncthreads();
#pragma unroll
        for (int ch = w; ch < BM / 8; ch += 4)
            gl_lds16(&A[(size_t)(m0 + ch * 8 + lr) * K + k0 + lc * 8], &As[ch * 512]);
#pragma unroll
        for (int ch = w; ch < BN / 8; ch += 4)
            gl_lds16(&Bt[(size_t)(n0 + ch * 8 + lr) * K + k0 + lc * 8], &Bs[ch * 512]);
        __syncthreads();   // drains vmcnt (gload_lds)
#pragma unroll
        for (int kk = 0; kk < 4; kk++) {
            short8 a[MR], b[NR];
#pragma unroll
            for (int i = 0; i < MR; i++)
                a[i] = *(const short8*)&As[(wr * WM + i * 32 + l31) * BK + kk * 16 + hk];
#pragma unroll
            for (int j = 0; j < NR; j++)
                b[j] = *(const short8*)&Bs[(wc * WN + j * 32 + l31) * BK + kk * 16 + hk];
#pragma unroll
            for (int i = 0; i < MR; i++)
#pragma unroll
                for (int j = 0; j < NR; j++)
                    acc[i][j] = __builtin_amdgcn_mfma_f32_32x32x16_bf16(a[i], b[j], acc[i][j], 0, 0, 0);
        }
    }
    int rbase = 4 * (lane >> 5);
    int bi = m0 >> 11;   // batch index
#pragma unroll
    for (int i = 0; i < MR; i++)
#pragma unroll
        for (int j = 0; j < NR; j++) {
            int col = n0 + wc * WN + j * 32 + l31;
            float gm = 1.f, bt = 0.f;
            if (FILM) {
                gm = gamma[bi * D_ + col];
                bt = beta[bi * D_ + col];
            }
#pragma unroll
            for (int r = 0; r < 16; r++) {
                int row = m0 + wr * WM + i * 32 + rbase + (r & 3) + 8 * (r >> 2);
                float v = acc[i][j][r];
                if (FILM) v = gm * v + bt;
                if constexpr (OBF)
                    ((short*)Cv)[(size_t)row * N + col] = f2bf(v);
                else
                    ((float*)Cv)[(size_t)row * N + col] = v;
            }
        }
}

// ================= mid: sliding-window conv -> xproj -> dt; 16 tok/block, 8 waves =================
__global__ __launch_bounds__(512) void mid_kernel(
    const short* __restrict__ xzb, const float* __restrict__ cw, const float* __restrict__ cb,
    const short* __restrict__ Wxt,   // [64][1024] bf16
    const short* __restrict__ Wdtt,  // [1024][32] bf16
    const float* __restrict__ bdt,
    short* __restrict__ ucb, float* __restrict__ xdbl, short* __restrict__ deltab) {
    constexpr int LDU = 1032;                        // 2064B pitch
    __shared__ __align__(16) short u[16 * LDU];      // 33 KB uc (bf16)
    __shared__ __align__(16) float xd2[2][16 * 68];  // 8.7 KB x_dbl partials
    int tid = threadIdx.x;
    int t0 = blockIdx.x * 16;
    int n0 = t0 & (N_ - 1);
    // ---- conv+SiLU: thread -> 8-wide e-chunk, 4 tokens; 7-row sliding window ----
    {
        int c8 = (tid & 127) * 8;      // e offset
        int base = (tid >> 7) * 4;     // first token of this thread's group
        float4 wv[8];
        float cbv[8];
#pragma unroll
        for (int j = 0; j < 8; j++) {
            wv[j] = *(const float4*)(cw + (c8 + j) * 4);
            cbv[j] = cb[c8 + j];
        }
        float uf[7][8];
#pragma unroll
        for (int j = 0; j < 7; j++) {
            short8 v = {0, 0, 0, 0, 0, 0, 0, 0};
            if (n0 + base - 3 + j >= 0)
                v = *(const short8*)&xzb[(size_t)(t0 + base - 3 + j) * (2 * E_) + c8];
#pragma unroll
            for (int q = 0; q < 8; q++) uf[j][q] = bf2f(v[q]);
        }
#pragma unroll
        for (int k = 0; k < 4; k++) {
            int n = base + k;
            short8 o;
#pragma unroll
            for (int q = 0; q < 8; q++) {
                float a = fmaf(wv[q].x, uf[k][q],
                          fmaf(wv[q].y, uf[k + 1][q],
                          fmaf(wv[q].z, uf[k + 2][q],
                          fmaf(wv[q].w, uf[k + 3][q], cbv[q]))));
                float v = a / (1.f + __expf(-a));
                o[q] = f2bf(v);
            }
            *(short8*)&ucb[(size_t)(t0 + n) * E_ + c8] = o;
            *(short8*)&u[n * LDU + c8] = o;
        }
    }
    __syncthreads();
    // ---- xproj: 8 waves; wave w -> cols [cg*16,+16), K-half kh; partials in xd2[kh] ----
    int lane = tid & 63, w = tid >> 6;
    int cg = w & 3, kh = w >> 2;
    int l15 = lane & 15, kq = (lane >> 4) * 8;
    f32x4 acc4 = {0.f, 0.f, 0.f, 0.f};
#pragma unroll 8
    for (int k0 = 0; k0 < 16; k0++) {
        int kk = kh * 512 + k0 * 32;
        short8 af = *(const short8*)&u[l15 * LDU + kk + kq];
        short8 bfr = *(const short8*)&Wxt[(size_t)(cg * 16 + l15) * E_ + kk + kq];
        acc4 = __builtin_amdgcn_mfma_f32_16x16x32_bf16(af, bfr, acc4, 0, 0, 0);
    }
#pragma unroll
    for (int j = 0; j < 4; j++)
        xd2[kh][((lane >> 4) * 4 + j) * 68 + cg * 16 + l15] = acc4[j];
    __syncthreads();
    // reduce K-halves, write x_dbl, keep sum in xd2[0]
    if (tid < 256) {
        int r = tid >> 4, c4 = (tid & 15) * 4;
        float4 a = *(const float4*)&xd2[0][r * 68 + c4];
        float4 b = *(const float4*)&xd2[1][r * 68 + c4];
        a.x += b.x; a.y += b.y; a.z += b.z; a.w += b.w;
        *(float4*)&xd2[0][r * 68 + c4] = a;
        *(float4*)&xdbl[(size_t)(t0 + r) * 64 + c4] = a;
    }
    __syncthreads();
    // ---- dt: 8 waves x 8 e-tiles of 16 ----
    float av[8];
    *(float4*)&av[0] = *(const float4*)&xd2[0][l15 * 68 + kq];
    *(float4*)&av[4] = *(const float4*)&xd2[0][l15 * 68 + kq + 4];
    short8 ab;
#pragma unroll
    for (int j = 0; j < 8; j++) ab[j] = f2bf(av[j]);
    int row4 = (lane >> 4) * 4;
#pragma unroll 4
    for (int t = 0; t < 8; t++) {
        int e = w * 128 + t * 16 + l15;
        short8 bb = *(const short8*)&Wdtt[(size_t)e * 32 + kq];
        f32x4 c4v = {0.f, 0.f, 0.f, 0.f};
        c4v = __builtin_amdgcn_mfma_f32_16x16x32_bf16(ab, bb, c4v, 0, 0, 0);
        float bv = bdt[e];
#pragma unroll
        for (int j = 0; j < 4; j++) {
            float xv = c4v[j] + bv;
            float sp = (xv > 20.f) ? xv : log1pf(__expf(xv));
            deltab[(size_t)(t0 + row4 + j) * E_ + e] = f2bf(sp);
        }
    }
}

// ---------------- chunked selective scan, s-in-registers (bf16 inputs) ----------------
__global__ __launch_bounds__(256) void scan_p1(const short* __restrict__ deltab,
                                               const short* __restrict__ ucb,
                                               const float* __restrict__ xdbl,
                                               const float* __restrict__ A_log,
                                               float* __restrict__ hend,
                                               float* __restrict__ cumd) {
    int blk = blockIdx.x;            // b*(NC_*4) + c*4 + eq
    int eq = blk & 3;
    int c = (blk >> 2) & (NC_ - 1);
    int b = blk >> 8;
    int tid = threadIdx.x;
    int e = eq * 256 + tid;
    __shared__ float Bsl[CH_][16];
    int base = (b * N_ + c * CH_) * 64;
    for (int i = tid; i < CH_ * 16; i += 256) {
        int n = i >> 4, col = i & 15;
        Bsl[n][col] = xdbl[base + n * 64 + R_ + col];
    }
    float Aes[16];
    const float4* al = (const float4*)(A_log + e * 16);
#pragma unroll
    for (int j = 0; j < 4; j++) {
        float4 a = al[j];
        Aes[j * 4 + 0] = -__expf(a.x);
        Aes[j * 4 + 1] = -__expf(a.y);
        Aes[j * 4 + 2] = -__expf(a.z);
        Aes[j * 4 + 3] = -__expf(a.w);
    }
    __syncthreads();
    float h[16];
#pragma unroll
    for (int s = 0; s < 16; s++) h[s] = 0.f;
    float cum = 0.f;
    const short* dp = deltab + (size_t)(b * N_ + c * CH_) * E_ + e;
    const short* up = ucb + (size_t)(b * N_ + c * CH_) * E_ + e;
#pragma unroll 2
    for (int n = 0; n < CH_; n++) {
        float dv = bf2f(dp[n * E_]);
        float uv = bf2f(up[n * E_]);
        float du = dv * uv;
        cum += dv;
        float Bl[16];
#pragma unroll
        for (int j = 0; j < 4; j++) *(float4*)&Bl[j * 4] = *(const float4*)&Bsl[n][j * 4];
#pragma unroll
        for (int s = 0; s < 16; s++) {
            float dA = __expf(dv * Aes[s]);
            h[s] = fmaf(dA, h[s], du * Bl[s]);
        }
    }
    size_t ob = (size_t)(b * NC_ + c) * 16 * E_ + e;
#pragma unroll
    for (int s = 0; s < 16; s++) hend[ob + (size_t)s * E_] = h[s];
    cumd[(size_t)(b * NC_ + c) * E_ + e] = cum;
}

// ---- comb: wave-parallel Kogge-Stone over chunks; block = (b, s, 64-e tile) ----
__global__ __launch_bounds__(256) void scan_comb(float* __restrict__ hend,
                                                 const float* __restrict__ cumd,
                                                 const float* __restrict__ A_log) {
    __shared__ float lh[64][65];   // [c][e]
    __shared__ float lp[64][65];
    int blk = blockIdx.x;          // b*256 + s*16 + et
    int et = blk & 15;
    int s = (blk >> 4) & 15;
    int b = blk >> 8;
    int e0 = et * 64;
    int tid = threadIdx.x;
    int lane = tid & 63, w = tid >> 6;
    for (int i = tid; i < 64 * 64; i += 256) {
        int c = i >> 6, e = i & 63;
        lh[c][e] = hend[((size_t)((b * NC_ + c) * 16) + s) * E_ + e0 + e];
        lp[c][e] = cumd[(size_t)(b * NC_ + c) * E_ + e0 + e];
    }
    __syncthreads();
#pragma unroll 4
    for (int q = 0; q < 16; q++) {
        int e = w * 16 + q;
        float Aes = -__expf(A_log[(e0 + e) * 16 + s]);
        float A = __expf(Aes * lp[lane][e]);
        float Bv = lh[lane][e];
#pragma unroll
        for (int off = 1; off < 64; off <<= 1) {
            float Ap = __shfl_up(A, off);
            float Bp = __shfl_up(Bv, off);
            if (lane >= off) {
                Bv = fmaf(A, Bp, Bv);
                A *= Ap;
            }
        }
        float hB = __shfl_up(Bv, 1);
        lh[lane][e] = (lane == 0) ? 0.f : hB;   // exclusive scan result
    }
    __syncthreads();
    for (int i = tid; i < 64 * 64; i += 256) {
        int c = i >> 6, e = i & 63;
        hend[((size_t)((b * NC_ + c) * 16) + s) * E_ + e0 + e] = lh[c][e];
    }
}

__global__ __launch_bounds__(256) void scan_p3(const short* __restrict__ deltab,
                                               const short* __restrict__ ucb,
                                               const float* __restrict__ xdbl,
                                               const short* __restrict__ xzb,
                                               const float* __restrict__ A_log,
                                               const float* __restrict__ D_skip,
                                               const float* __restrict__ hend,
                                               short* __restrict__ yb) {
    int blk = blockIdx.x;
    int eq = blk & 3;
    int c = (blk >> 2) & (NC_ - 1);
    int b = blk >> 8;
    int tid = threadIdx.x;
    int e = eq * 256 + tid;
    __shared__ float Bsl[CH_][16];
    __shared__ float Csl[CH_][16];
    int base = (b * N_ + c * CH_) * 64;
    for (int i = tid; i < CH_ * 32; i += 256) {
        int n = i >> 5, col = i & 31;
        float v = xdbl[base + n * 64 + R_ + col];
        if (col < 16) Bsl[n][col] = v;
        else Csl[n][col - 16] = v;
    }
    float Aes[16];
    const float4* al = (const float4*)(A_log + e * 16);
#pragma unroll
    for (int j = 0; j < 4; j++) {
        float4 a = al[j];
        Aes[j * 4 + 0] = -__expf(a.x);
        Aes[j * 4 + 1] = -__expf(a.y);
        Aes[j * 4 + 2] = -__expf(a.z);
        Aes[j * 4 + 3] = -__expf(a.w);
    }
    float dsk = D_skip[e];
    float h[16];
    size_t ob = (size_t)(b * NC_ + c) * 16 * E_ + e;
#pragma unroll
    for (int s = 0; s < 16; s++) h[s] = hend[ob + (size_t)s * E_];
    __syncthreads();
    const short* dp = deltab + (size_t)(b * N_ + c * CH_) * E_ + e;
    const short* up = ucb + (size_t)(b * N_ + c * CH_) * E_ + e;
    const short* zp = xzb + (size_t)(b * N_ + c * CH_) * (2 * E_) + E_ + e;
    short* yp = yb + (size_t)(b * N_ + c * CH_) * E_ + e;
#pragma unroll 2
    for (int n = 0; n < CH_; n++) {
        float dv = bf2f(dp[n * E_]);
        float uv = bf2f(up[n * E_]);
        float du = dv * uv;
        float Bl[16], Cl[16];
#pragma unroll
        for (int j = 0; j < 4; j++) {
            *(float4*)&Bl[j * 4] = *(const float4*)&Bsl[n][j * 4];
            *(float4*)&Cl[j * 4] = *(const float4*)&Csl[n][j * 4];
        }
        float y = 0.f;
#pragma unroll
        for (int s = 0; s < 16; s++) {
            float dA = __expf(dv * Aes[s]);
            h[s] = fmaf(dA, h[s], du * Bl[s]);
            y = fmaf(h[s], Cl[s], y);
        }
        float zv = bf2f(zp[n * 2 * E_]);
        float yy = y + dsk * uv;
        yy = yy * (zv / (1.f + __expf(-zv)));
        yp[n * E_] = f2bf(yy);
    }
}

extern "C" void kernel_launch(void* const* d_in, const int* in_sizes, int n_in,
                              void* d_out, int out_size, void* d_ws, size_t ws_size,
                              hipStream_t stream) {
    const float* x       = (const float*)d_in[0];
    const float* cond    = (const float*)d_in[1];
    const float* ln_g    = (const float*)d_in[2];
    const float* ln_b    = (const float*)d_in[3];
    const float* W_in    = (const float*)d_in[4];
    const float* conv_w  = (const float*)d_in[5];
    const float* conv_b  = (const float*)d_in[6];
    const float* W_x     = (const float*)d_in[7];
    const float* W_dt    = (const float*)d_in[8];
    const float* b_dt    = (const float*)d_in[9];
    const float* A_log   = (const float*)d_in[10];
    const float* D_skip  = (const float*)d_in[11];
    const float* W_out   = (const float*)d_in[12];
    const float* film_gw = (const float*)d_in[13];
    const float* film_gb = (const float*)d_in[14];
    const float* film_bw = (const float*)d_in[15];
    const float* film_bb = (const float*)d_in[16];
    float* out = (float*)d_out;

    float* ws = (float*)d_ws;
    float* xdbl  = ws;                       //   262,144 f
    float* gamma = xdbl + 262144;            //     1,024 f
    float* beta  = gamma + 1024;             //     1,024 f
    float* hend  = beta + 1024;              // 2,097,152 f  (B*NC*S*E)
    float* cumd  = hend + 2097152;           //   131,072 f  (B*NC*E)
    short* xzb   = (short*)(cumd + 131072);  // 8,388,608 sh (bf16 xz)
    short* ucb   = xzb + 8388608;            // 4,194,304 sh (bf16 uc)
    short* deltab = ucb + 4194304;           // 4,194,304 sh (bf16 delta)
    short* Wint  = deltab + 4194304;         // 1,048,576 sh
    short* Woutt = Wint + 1048576;           //   524,288 sh
    short* yb    = Woutt + 524288;           // 4,194,304 sh
    short* Wxt   = yb + 4194304;             //    65,536 sh
    short* Wdtt  = Wxt + 65536;              //    32,768 sh
    short* xnb   = Wdtt + 32768;             // 2,097,152 sh (bf16 LN(x))

    // prep: film2 + 4 weight transposes + LN stats+apply, one launch (5736 blocks)
    prep_kernel<<<5736, 256, 0, stream>>>(
        x, xnb, W_in, Wint, W_out, Woutt, W_x, Wxt, W_dt, Wdtt,
        cond, ln_g, ln_b, film_gw, film_gb, film_bw, film_bb, gamma, beta);

    // xz = xn @ W_in   [4096,512]x[512,2048], all-gload_lds, bf16 out, XCD-swizzled
    gemm_bf16<128, 128, false, true>
        <<<512, 256, 0, stream>>>(
            xnb, Wint, xzb, B_ * N_, 2 * E_, D_, nullptr, nullptr);

    // conv+silu -> xproj -> dt, fused; 256 blocks x 8 waves, 16 tokens each
    mid_kernel<<<B_ * N_ / 16, 512, 0, stream>>>(
        xzb, conv_w, conv_b, Wxt, Wdtt, b_dt, ucb, xdbl, deltab);

    scan_p1<<<B_ * NC_ * 4, 256, 0, stream>>>(deltab, ucb, xdbl, A_log, hend, cumd);
    scan_comb<<<B_ * S_ * (E_ / 64), 256, 0, stream>>>(hend, cumd, A_log);
    scan_p3<<<B_ * NC_ * 4, 256, 0, stream>>>(deltab, ucb, xdbl, xzb, A_log, D_skip, hend, yb);

    // out = FiLM(y @ W_out)   [4096,1024]x[1024,512], 64x64 tiles (2 blocks/CU), XCD-swizzled
    gemm_bf16<64, 64, true, false>
        <<<512, 256, 0, stream>>>(
            yb, Woutt, out, B_ * N_, D_, E_, gamma, beta);
}

// Round 14
// 128.503 us; speedup vs baseline: 4.6050x; 1.0648x over previous
//
#include <hip/hip_runtime.h>
#include <hip/hip_bf16.h>
#include <math.h>

#define B_ 2
#define N_ 2048
#define D_ 512
#define E_ 1024
#define S_ 16
#define R_ 32
#define C_ 512
#define CH_ 32
#define NC_ (N_ / CH_)   // 64 chunks

using short8 = __attribute__((ext_vector_type(8))) short;
using f32x4  = __attribute__((ext_vector_type(4))) float;
using f32x16 = __attribute__((ext_vector_type(16))) float;

__device__ __forceinline__ short f2bf(float f) {
    union { float f; unsigned u; } x; x.f = f;
    unsigned r = (x.u + 0x7fffu + ((x.u >> 16) & 1u)) >> 16;
    return (short)r;
}
__device__ __forceinline__ float bf2f(short s) {
    union { unsigned u; float f; } x;
    x.u = ((unsigned)(unsigned short)s) << 16;
    return x.f;
}
// wave-level async global->LDS, 16B per lane (lds dest wave-uniform base + lane*16)
__device__ __forceinline__ void gl_lds16(const void* g, void* l) {
    __builtin_amdgcn_global_load_lds((const __attribute__((address_space(1))) void*)g,
                                     (__attribute__((address_space(3))) void*)l, 16, 0, 0);
}

__device__ __forceinline__ void transpose32(const float* __restrict__ W, short* __restrict__ Wt,
                                            int K, int N, int bx, int by, float (*t)[33], int tid) {
    int n0 = bx * 32, k0 = by * 32;
    int c = tid & 31, rr0 = tid >> 5;
#pragma unroll
    for (int rr = rr0; rr < 32; rr += 8)
        t[rr][c] = W[(size_t)(k0 + rr) * N + n0 + c];
    __syncthreads();
#pragma unroll
    for (int rr = rr0; rr < 32; rr += 8)
        Wt[(size_t)(n0 + rr) * K + k0 + c] = f2bf(t[c][rr]);
}

// ================= K1: LN stats+apply (wave/token) | W_in^T =================
// blocks [0,1024): LN 4 tokens/block; [1024,2048): W_in transpose
__global__ __launch_bounds__(256) void prep1_kernel(
    const float* __restrict__ x, short* __restrict__ xnb,
    const float* __restrict__ lng, const float* __restrict__ lnb,
    const float* __restrict__ W_in, short* __restrict__ Wint) {
    __shared__ __align__(16) float smem[32 * 33];
    int bid = blockIdx.x;
    int tid = threadIdx.x;
    if (bid < 1024) {
        int t = bid * 4 + (tid >> 6);
        int lane = tid & 63;
        const float* src = x + (size_t)t * D_ + lane * 8;
        float4 v0 = *(const float4*)src;
        float4 v1 = *(const float4*)(src + 4);
        float s = v0.x + v0.y + v0.z + v0.w + v1.x + v1.y + v1.z + v1.w;
        float s2 = v0.x * v0.x;
        s2 = fmaf(v0.y, v0.y, s2); s2 = fmaf(v0.z, v0.z, s2); s2 = fmaf(v0.w, v0.w, s2);
        s2 = fmaf(v1.x, v1.x, s2); s2 = fmaf(v1.y, v1.y, s2);
        s2 = fmaf(v1.z, v1.z, s2); s2 = fmaf(v1.w, v1.w, s2);
#pragma unroll
        for (int o = 32; o >= 1; o >>= 1) {
            s += __shfl_xor(s, o);
            s2 += __shfl_xor(s2, o);
        }
        float mu = s * (1.f / (float)D_);
        float var = s2 * (1.f / (float)D_) - mu * mu;
        float rs = rsqrtf(var + 1e-5f);
        float4 g0 = *(const float4*)(lng + lane * 8);
        float4 g1 = *(const float4*)(lng + lane * 8 + 4);
        float4 b0 = *(const float4*)(lnb + lane * 8);
        float4 b1 = *(const float4*)(lnb + lane * 8 + 4);
        short8 o;
        o[0] = f2bf((v0.x - mu) * rs * g0.x + b0.x);
        o[1] = f2bf((v0.y - mu) * rs * g0.y + b0.y);
        o[2] = f2bf((v0.z - mu) * rs * g0.z + b0.z);
        o[3] = f2bf((v0.w - mu) * rs * g0.w + b0.w);
        o[4] = f2bf((v1.x - mu) * rs * g1.x + b1.x);
        o[5] = f2bf((v1.y - mu) * rs * g1.y + b1.y);
        o[6] = f2bf((v1.z - mu) * rs * g1.z + b1.z);
        o[7] = f2bf((v1.w - mu) * rs * g1.w + b1.w);
        *(short8*)(xnb + (size_t)t * D_ + lane * 8) = o;
    } else {
        int r = bid - 1024;
        transpose32(W_in, Wint, 512, 2048, r % 64, r / 64, (float(*)[33])smem, tid);
    }
}

// ================= K2 hybrid: gemm1 tiles | film | W_out^T | W_x^T | W_dt^T =================
// [0,512): gemm xz = xn@W_in (bf16 out, XCD-swizzled); [512,520): film;
// [520,1032): W_out^T; [1032,1096): W_x^T; [1096,1128): W_dt^T
__global__ __launch_bounds__(256) void gemm1_hybrid(
    const short* __restrict__ A, const short* __restrict__ Bt, short* __restrict__ Cb,
    const float* __restrict__ W_out, short* __restrict__ Woutt,
    const float* __restrict__ W_x, short* __restrict__ Wxt,
    const float* __restrict__ W_dt, short* __restrict__ Wdtt,
    const float* __restrict__ cond,
    const float* __restrict__ gw, const float* __restrict__ gb,
    const float* __restrict__ bw, const float* __restrict__ bb,
    float* __restrict__ gamma, float* __restrict__ beta) {
    __shared__ __align__(16) char smem[32768];
    int bid = blockIdx.x;
    int tid = threadIdx.x;
    if (bid < 512) {
        constexpr int BM = 128, BN = 128, BK = 64;
        constexpr int M = 4096, N = 2048, K = 512;
        short* As = (short*)smem;          // [128][64]
        short* Bs = As + BM * BK;
        int lane = tid & 63, w = tid >> 6;
        int wr = w >> 1, wc = w & 1;
        int swz = (bid & 7) * 64 + (bid >> 3);
        int m0 = (swz >> 4) * BM, n0 = (swz & 15) * BN;
        int lr = lane >> 3, lc = lane & 7;
        f32x16 acc[2][2];
#pragma unroll
        for (int i = 0; i < 2; i++)
#pragma unroll
            for (int j = 0; j < 2; j++)
#pragma unroll
                for (int r = 0; r < 16; r++) acc[i][j][r] = 0.f;
        int l31 = lane & 31, hk = (lane >> 5) * 8;
        for (int k0 = 0; k0 < K; k0 += BK) {
            __syncthreads();
#pragma unroll
            for (int ch = w; ch < BM / 8; ch += 4)
                gl_lds16(&A[(size_t)(m0 + ch * 8 + lr) * K + k0 + lc * 8], &As[ch * 512]);
#pragma unroll
            for (int ch = w; ch < BN / 8; ch += 4)
                gl_lds16(&Bt[(size_t)(n0 + ch * 8 + lr) * K + k0 + lc * 8], &Bs[ch * 512]);
            __syncthreads();
#pragma unroll
            for (int kk = 0; kk < 4; kk++) {
                short8 a[2], b[2];
#pragma unroll
                for (int i = 0; i < 2; i++)
                    a[i] = *(const short8*)&As[(wr * 64 + i * 32 + l31) * BK + kk * 16 + hk];
#pragma unroll
                for (int j = 0; j < 2; j++)
                    b[j] = *(const short8*)&Bs[(wc * 64 + j * 32 + l31) * BK + kk * 16 + hk];
#pragma unroll
                for (int i = 0; i < 2; i++)
#pragma unroll
                    for (int j = 0; j < 2; j++)
                        acc[i][j] = __builtin_amdgcn_mfma_f32_32x32x16_bf16(a[i], b[j], acc[i][j], 0, 0, 0);
            }
        }
        int rbase = 4 * (lane >> 5);
#pragma unroll
        for (int i = 0; i < 2; i++)
#pragma unroll
            for (int j = 0; j < 2; j++) {
                int col = n0 + wc * 64 + j * 32 + l31;
#pragma unroll
                for (int r = 0; r < 16; r++) {
                    int row = m0 + wr * 64 + i * 32 + rbase + (r & 3) + 8 * (r >> 2);
                    Cb[(size_t)row * N + col] = f2bf(acc[i][j][r]);
                }
            }
    } else if (bid < 520) {
        // ---- film: d0 = (bid-512)*64 ----
        float* cs = (float*)smem;           // [2][512]
        float* red = (float*)smem + 1024;   // [4][64][4]
        int d0 = (bid - 512) * 64;
#pragma unroll
        for (int i = tid; i < 2 * C_ / 4; i += 256) {
            int b = i >> 7;
            int c4 = (i & 127) * 4;
            *(float4*)&cs[b * C_ + c4] = *(const float4*)(cond + (size_t)b * C_ + c4);
        }
        __syncthreads();
        int dl = tid & 63, ks = tid >> 6;
        int d = d0 + dl;
        float g0 = 0.f, g1 = 0.f, bt0 = 0.f, bt1 = 0.f;
#pragma unroll 4
        for (int k = ks * 128; k < ks * 128 + 128; k++) {
            float wg = gw[(size_t)k * D_ + d];
            float wb = bw[(size_t)k * D_ + d];
            float c0 = cs[k], c1 = cs[C_ + k];
            g0 = fmaf(c0, wg, g0);
            g1 = fmaf(c1, wg, g1);
            bt0 = fmaf(c0, wb, bt0);
            bt1 = fmaf(c1, wb, bt1);
        }
        red[(ks * 64 + dl) * 4 + 0] = g0; red[(ks * 64 + dl) * 4 + 1] = g1;
        red[(ks * 64 + dl) * 4 + 2] = bt0; red[(ks * 64 + dl) * 4 + 3] = bt1;
        __syncthreads();
        if (ks == 0) {
            float s0 = 0.f, s1 = 0.f, s2 = 0.f, s3 = 0.f;
#pragma unroll
            for (int q = 0; q < 4; q++) {
                s0 += red[(q * 64 + dl) * 4 + 0]; s1 += red[(q * 64 + dl) * 4 + 1];
                s2 += red[(q * 64 + dl) * 4 + 2]; s3 += red[(q * 64 + dl) * 4 + 3];
            }
            float gbv = gb[d], bbv = bb[d];
            gamma[d] = s0 + gbv;
            gamma[D_ + d] = s1 + gbv;
            beta[d] = s2 + bbv;
            beta[D_ + d] = s3 + bbv;
        }
    } else if (bid < 1032) {
        int r = bid - 520;
        transpose32(W_out, Woutt, 1024, 512, r % 16, r / 16, (float(*)[33])smem, tid);
    } else if (bid < 1096) {
        int r = bid - 1032;
        transpose32(W_x, Wxt, 1024, 64, r % 2, r / 2, (float(*)[33])smem, tid);
    } else {
        int r = bid - 1096;
        transpose32(W_dt, Wdtt, 32, 1024, r, 0, (float(*)[33])smem, tid);
    }
}

// ---------------- gemm2: C[M][N] = A[M][K] * Bt[N][K]^T, FiLM, fp32 out ----------------
template <int BM, int BN>
__global__ __launch_bounds__(256) void gemm2_kernel(
    const short* __restrict__ A, const short* __restrict__ Bt, float* __restrict__ Cf,
    int M, int N, int K,
    const float* __restrict__ gamma, const float* __restrict__ beta) {
    constexpr int BK = 64;
    constexpr int WM = BM / 2, WN = BN / 2;
    constexpr int MR = WM / 32, NR = WN / 32;
    __shared__ __align__(16) short As[BM * BK];
    __shared__ __align__(16) short Bs[BN * BK];
    int tid = threadIdx.x;
    int lane = tid & 63, w = tid >> 6;
    int wr = w >> 1, wc = w & 1;
    int lid = blockIdx.x;
    int chunk = gridDim.x >> 3;
    int swz = (lid & 7) * chunk + (lid >> 3);
    int ntiles = N / BN;
    int m0 = (swz / ntiles) * BM, n0 = (swz % ntiles) * BN;
    int lr = lane >> 3, lc = lane & 7;

    f32x16 acc[MR][NR];
#pragma unroll
    for (int i = 0; i < MR; i++)
#pragma unroll
        for (int j = 0; j < NR; j++)
#pragma unroll
            for (int r = 0; r < 16; r++) acc[i][j][r] = 0.f;

    int l31 = lane & 31, hk = (lane >> 5) * 8;

    for (int k0 = 0; k0 < K; k0 += BK) {
        __syncthreads();
#pragma unroll
        for (int ch = w; ch < BM / 8; ch += 4)
            gl_lds16(&A[(size_t)(m0 + ch * 8 + lr) * K + k0 + lc * 8], &As[ch * 512]);
#pragma unroll
        for (int ch = w; ch < BN / 8; ch += 4)
            gl_lds16(&Bt[(size_t)(n0 + ch * 8 + lr) * K + k0 + lc * 8], &Bs[ch * 512]);
        __syncthreads();
#pragma unroll
        for (int kk = 0; kk < 4; kk++) {
            short8 a[MR], b[NR];
#pragma unroll
            for (int i = 0; i < MR; i++)
                a[i] = *(const short8*)&As[(wr * WM + i * 32 + l31) * BK + kk * 16 + hk];
#pragma unroll
            for (int j = 0; j < NR; j++)
                b[j] = *(const short8*)&Bs[(wc * WN + j * 32 + l31) * BK + kk * 16 + hk];
#pragma unroll
            for (int i = 0; i < MR; i++)
#pragma unroll
                for (int j = 0; j < NR; j++)
                    acc[i][j] = __builtin_amdgcn_mfma_f32_32x32x16_bf16(a[i], b[j], acc[i][j], 0, 0, 0);
        }
    }
    int rbase = 4 * (lane >> 5);
    int bi = m0 >> 11;
#pragma unroll
    for (int i = 0; i < MR; i++)
#pragma unroll
        for (int j = 0; j < NR; j++) {
            int col = n0 + wc * WN + j * 32 + l31;
            float gm = gamma[bi * D_ + col];
            float bt = beta[bi * D_ + col];
#pragma unroll
            for (int r = 0; r < 16; r++) {
                int row = m0 + wr * WM + i * 32 + rbase + (r & 3) + 8 * (r >> 2);
                Cf[(size_t)row * N + col] = gm * acc[i][j][r] + bt;
            }
        }
}

// ================= mid: sliding-window conv -> xproj -> dt; 16 tok/block, 8 waves =================
__global__ __launch_bounds__(512) void mid_kernel(
    const short* __restrict__ xzb, const float* __restrict__ cw, const float* __restrict__ cb,
    const short* __restrict__ Wxt,   // [64][1024] bf16
    const short* __restrict__ Wdtt,  // [1024][32] bf16
    const float* __restrict__ bdt,
    short* __restrict__ ucb, float* __restrict__ xdbl, short* __restrict__ deltab) {
    constexpr int LDU = 1032;                        // 2064B pitch
    __shared__ __align__(16) short u[16 * LDU];      // 33 KB uc (bf16)
    __shared__ __align__(16) float xd2[2][16 * 68];  // 8.7 KB x_dbl partials
    int tid = threadIdx.x;
    int t0 = blockIdx.x * 16;
    int n0 = t0 & (N_ - 1);
    // ---- conv+SiLU: thread -> 8-wide e-chunk, 4 tokens; 7-row sliding window ----
    {
        int c8 = (tid & 127) * 8;      // e offset
        int base = (tid >> 7) * 4;     // first token of this thread's group
        float4 wv[8];
        float cbv[8];
#pragma unroll
        for (int j = 0; j < 8; j++) {
            wv[j] = *(const float4*)(cw + (c8 + j) * 4);
            cbv[j] = cb[c8 + j];
        }
        float uf[7][8];
#pragma unroll
        for (int j = 0; j < 7; j++) {
            short8 v = {0, 0, 0, 0, 0, 0, 0, 0};
            if (n0 + base - 3 + j >= 0)
                v = *(const short8*)&xzb[(size_t)(t0 + base - 3 + j) * (2 * E_) + c8];
#pragma unroll
            for (int q = 0; q < 8; q++) uf[j][q] = bf2f(v[q]);
        }
#pragma unroll
        for (int k = 0; k < 4; k++) {
            int n = base + k;
            short8 o;
#pragma unroll
            for (int q = 0; q < 8; q++) {
                float a = fmaf(wv[q].x, uf[k][q],
                          fmaf(wv[q].y, uf[k + 1][q],
                          fmaf(wv[q].z, uf[k + 2][q],
                          fmaf(wv[q].w, uf[k + 3][q], cbv[q]))));
                float v = a / (1.f + __expf(-a));
                o[q] = f2bf(v);
            }
            *(short8*)&ucb[(size_t)(t0 + n) * E_ + c8] = o;
            *(short8*)&u[n * LDU + c8] = o;
        }
    }
    __syncthreads();
    // ---- xproj: 8 waves; wave w -> cols [cg*16,+16), K-half kh; partials in xd2[kh] ----
    int lane = tid & 63, w = tid >> 6;
    int cg = w & 3, kh = w >> 2;
    int l15 = lane & 15, kq = (lane >> 4) * 8;
    f32x4 acc4 = {0.f, 0.f, 0.f, 0.f};
#pragma unroll 8
    for (int k0 = 0; k0 < 16; k0++) {
        int kk = kh * 512 + k0 * 32;
        short8 af = *(const short8*)&u[l15 * LDU + kk + kq];
        short8 bfr = *(const short8*)&Wxt[(size_t)(cg * 16 + l15) * E_ + kk + kq];
        acc4 = __builtin_amdgcn_mfma_f32_16x16x32_bf16(af, bfr, acc4, 0, 0, 0);
    }
#pragma unroll
    for (int j = 0; j < 4; j++)
        xd2[kh][((lane >> 4) * 4 + j) * 68 + cg * 16 + l15] = acc4[j];
    __syncthreads();
    // reduce K-halves, write x_dbl, keep sum in xd2[0]
    if (tid < 256) {
        int r = tid >> 4, c4 = (tid & 15) * 4;
        float4 a = *(const float4*)&xd2[0][r * 68 + c4];
        float4 b = *(const float4*)&xd2[1][r * 68 + c4];
        a.x += b.x; a.y += b.y; a.z += b.z; a.w += b.w;
        *(float4*)&xd2[0][r * 68 + c4] = a;
        *(float4*)&xdbl[(size_t)(t0 + r) * 64 + c4] = a;
    }
    __syncthreads();
    // ---- dt: 8 waves x 8 e-tiles of 16 ----
    float av[8];
    *(float4*)&av[0] = *(const float4*)&xd2[0][l15 * 68 + kq];
    *(float4*)&av[4] = *(const float4*)&xd2[0][l15 * 68 + kq + 4];
    short8 ab;
#pragma unroll
    for (int j = 0; j < 8; j++) ab[j] = f2bf(av[j]);
    int row4 = (lane >> 4) * 4;
#pragma unroll 4
    for (int t = 0; t < 8; t++) {
        int e = w * 128 + t * 16 + l15;
        short8 bb = *(const short8*)&Wdtt[(size_t)e * 32 + kq];
        f32x4 c4v = {0.f, 0.f, 0.f, 0.f};
        c4v = __builtin_amdgcn_mfma_f32_16x16x32_bf16(ab, bb, c4v, 0, 0, 0);
        float bv = bdt[e];
#pragma unroll
        for (int j = 0; j < 4; j++) {
            float xv = c4v[j] + bv;
            float sp = (xv > 20.f) ? xv : log1pf(__expf(xv));
            deltab[(size_t)(t0 + row4 + j) * E_ + e] = f2bf(sp);
        }
    }
}

// ---------------- chunked selective scan, s-in-registers (bf16 inputs, bf16 hend) ----------------
__global__ __launch_bounds__(256) void scan_p1(const short* __restrict__ deltab,
                                               const short* __restrict__ ucb,
                                               const float* __restrict__ xdbl,
                                               const float* __restrict__ A_log,
                                               short* __restrict__ hend,
                                               float* __restrict__ cumd) {
    int blk = blockIdx.x;            // b*(NC_*4) + c*4 + eq
    int eq = blk & 3;
    int c = (blk >> 2) & (NC_ - 1);
    int b = blk >> 8;
    int tid = threadIdx.x;
    int e = eq * 256 + tid;
    __shared__ float Bsl[CH_][16];
    int base = (b * N_ + c * CH_) * 64;
    for (int i = tid; i < CH_ * 16; i += 256) {
        int n = i >> 4, col = i & 15;
        Bsl[n][col] = xdbl[base + n * 64 + R_ + col];
    }
    float Aes[16];
    const float4* al = (const float4*)(A_log + e * 16);
#pragma unroll
    for (int j = 0; j < 4; j++) {
        float4 a = al[j];
        Aes[j * 4 + 0] = -__expf(a.x);
        Aes[j * 4 + 1] = -__expf(a.y);
        Aes[j * 4 + 2] = -__expf(a.z);
        Aes[j * 4 + 3] = -__expf(a.w);
    }
    __syncthreads();
    float h[16];
#pragma unroll
    for (int s = 0; s < 16; s++) h[s] = 0.f;
    float cum = 0.f;
    const short* dp = deltab + (size_t)(b * N_ + c * CH_) * E_ + e;
    const short* up = ucb + (size_t)(b * N_ + c * CH_) * E_ + e;
#pragma unroll 2
    for (int n = 0; n < CH_; n++) {
        float dv = bf2f(dp[n * E_]);
        float uv = bf2f(up[n * E_]);
        float du = dv * uv;
        cum += dv;
        float Bl[16];
#pragma unroll
        for (int j = 0; j < 4; j++) *(float4*)&Bl[j * 4] = *(const float4*)&Bsl[n][j * 4];
#pragma unroll
        for (int s = 0; s < 16; s++) {
            float dA = __expf(dv * Aes[s]);
            h[s] = fmaf(dA, h[s], du * Bl[s]);
        }
    }
    size_t ob = (size_t)(b * NC_ + c) * 16 * E_ + e;
#pragma unroll
    for (int s = 0; s < 16; s++) hend[ob + (size_t)s * E_] = f2bf(h[s]);
    cumd[(size_t)(b * NC_ + c) * E_ + e] = cum;
}

// ---- comb: wave-parallel Kogge-Stone over chunks; block = (b, s, 64-e tile) ----
__global__ __launch_bounds__(256) void scan_comb(short* __restrict__ hend,
                                                 const float* __restrict__ cumd,
                                                 const float* __restrict__ A_log) {
    __shared__ float lh[64][65];   // [c][e]
    __shared__ float lp[64][65];
    int blk = blockIdx.x;          // b*256 + s*16 + et
    int et = blk & 15;
    int s = (blk >> 4) & 15;
    int b = blk >> 8;
    int e0 = et * 64;
    int tid = threadIdx.x;
    int lane = tid & 63, w = tid >> 6;
    for (int i = tid; i < 64 * 64; i += 256) {
        int c = i >> 6, e = i & 63;
        lh[c][e] = bf2f(hend[((size_t)((b * NC_ + c) * 16) + s) * E_ + e0 + e]);
        lp[c][e] = cumd[(size_t)(b * NC_ + c) * E_ + e0 + e];
    }
    __syncthreads();
#pragma unroll 4
    for (int q = 0; q < 16; q++) {
        int e = w * 16 + q;
        float Aes = -__expf(A_log[(e0 + e) * 16 + s]);
        float A = __expf(Aes * lp[lane][e]);
        float Bv = lh[lane][e];
#pragma unroll
        for (int off = 1; off < 64; off <<= 1) {
            float Ap = __shfl_up(A, off);
            float Bp = __shfl_up(Bv, off);
            if (lane >= off) {
                Bv = fmaf(A, Bp, Bv);
                A *= Ap;
            }
        }
        float hB = __shfl_up(Bv, 1);
        lh[lane][e] = (lane == 0) ? 0.f : hB;   // exclusive scan result
    }
    __syncthreads();
    for (int i = tid; i < 64 * 64; i += 256) {
        int c = i >> 6, e = i & 63;
        hend[((size_t)((b * NC_ + c) * 16) + s) * E_ + e0 + e] = f2bf(lh[c][e]);
    }
}

__global__ __launch_bounds__(256) void scan_p3(const short* __restrict__ deltab,
                                               const short* __restrict__ ucb,
                                               const float* __restrict__ xdbl,
                                               const short* __restrict__ xzb,
                                               const float* __restrict__ A_log,
                                               const float* __restrict__ D_skip,
                                               const short* __restrict__ hend,
                                               short* __restrict__ yb) {
    int blk = blockIdx.x;
    int eq = blk & 3;
    int c = (blk >> 2) & (NC_ - 1);
    int b = blk >> 8;
    int tid = threadIdx.x;
    int e = eq * 256 + tid;
    __shared__ float Bsl[CH_][16];
    __shared__ float Csl[CH_][16];
    int base = (b * N_ + c * CH_) * 64;
    for (int i = tid; i < CH_ * 32; i += 256) {
        int n = i >> 5, col = i & 31;
        float v = xdbl[base + n * 64 + R_ + col];
        if (col < 16) Bsl[n][col] = v;
        else Csl[n][col - 16] = v;
    }
    float Aes[16];
    const float4* al = (const float4*)(A_log + e * 16);
#pragma unroll
    for (int j = 0; j < 4; j++) {
        float4 a = al[j];
        Aes[j * 4 + 0] = -__expf(a.x);
        Aes[j * 4 + 1] = -__expf(a.y);
        Aes[j * 4 + 2] = -__expf(a.z);
        Aes[j * 4 + 3] = -__expf(a.w);
    }
    float dsk = D_skip[e];
    float h[16];
    size_t ob = (size_t)(b * NC_ + c) * 16 * E_ + e;
#pragma unroll
    for (int s = 0; s < 16; s++) h[s] = bf2f(hend[ob + (size_t)s * E_]);
    __syncthreads();
    const short* dp = deltab + (size_t)(b * N_ + c * CH_) * E_ + e;
    const short* up = ucb + (size_t)(b * N_ + c * CH_) * E_ + e;
    const short* zp = xzb + (size_t)(b * N_ + c * CH_) * (2 * E_) + E_ + e;
    short* yp = yb + (size_t)(b * N_ + c * CH_) * E_ + e;
#pragma unroll 2
    for (int n = 0; n < CH_; n++) {
        float dv = bf2f(dp[n * E_]);
        float uv = bf2f(up[n * E_]);
        float du = dv * uv;
        float Bl[16], Cl[16];
#pragma unroll
        for (int j = 0; j < 4; j++) {
            *(float4*)&Bl[j * 4] = *(const float4*)&Bsl[n][j * 4];
            *(float4*)&Cl[j * 4] = *(const float4*)&Csl[n][j * 4];
        }
        float y = 0.f;
#pragma unroll
        for (int s = 0; s < 16; s++) {
            float dA = __expf(dv * Aes[s]);
            h[s] = fmaf(dA, h[s], du * Bl[s]);
            y = fmaf(h[s], Cl[s], y);
        }
        float zv = bf2f(zp[n * 2 * E_]);
        float yy = y + dsk * uv;
        yy = yy * (zv / (1.f + __expf(-zv)));
        yp[n * E_] = f2bf(yy);
    }
}

extern "C" void kernel_launch(void* const* d_in, const int* in_sizes, int n_in,
                              void* d_out, int out_size, void* d_ws, size_t ws_size,
                              hipStream_t stream) {
    const float* x       = (const float*)d_in[0];
    const float* cond    = (const float*)d_in[1];
    const float* ln_g    = (const float*)d_in[2];
    const float* ln_b    = (const float*)d_in[3];
    const float* W_in    = (const float*)d_in[4];
    const float* conv_w  = (const float*)d_in[5];
    const float* conv_b  = (const float*)d_in[6];
    const float* W_x     = (const float*)d_in[7];
    const float* W_dt    = (const float*)d_in[8];
    const float* b_dt    = (const float*)d_in[9];
    const float* A_log   = (const float*)d_in[10];
    const float* D_skip  = (const float*)d_in[11];
    const float* W_out   = (const float*)d_in[12];
    const float* film_gw = (const float*)d_in[13];
    const float* film_gb = (const float*)d_in[14];
    const float* film_bw = (const float*)d_in[15];
    const float* film_bb = (const float*)d_in[16];
    float* out = (float*)d_out;

    float* ws = (float*)d_ws;
    float* xdbl  = ws;                       //   262,144 f
    float* gamma = xdbl + 262144;            //     1,024 f
    float* beta  = gamma + 1024;             //     1,024 f
    float* cumd  = beta + 1024;              //   131,072 f  (B*NC*E)
    short* hend  = (short*)(cumd + 131072);  // 2,097,152 sh (bf16, B*NC*S*E)
    short* xzb   = hend + 2097152;           // 8,388,608 sh (bf16 xz)
    short* ucb   = xzb + 8388608;            // 4,194,304 sh (bf16 uc)
    short* deltab = ucb + 4194304;           // 4,194,304 sh (bf16 delta)
    short* Wint  = deltab + 4194304;         // 1,048,576 sh
    short* Woutt = Wint + 1048576;           //   524,288 sh
    short* yb    = Woutt + 524288;           // 4,194,304 sh
    short* Wxt   = yb + 4194304;             //    65,536 sh
    short* Wdtt  = Wxt + 65536;              //    32,768 sh
    short* xnb   = Wdtt + 32768;             // 2,097,152 sh (bf16 LN(x))

    // K1: LN stats+apply + W_in^T (2048 blocks)
    prep1_kernel<<<2048, 256, 0, stream>>>(x, xnb, ln_g, ln_b, W_in, Wint);

    // K2: gemm1 (512 XCD-swizzled tiles) + film + W_out^T + W_x^T + W_dt^T (1128 blocks)
    gemm1_hybrid<<<1128, 256, 0, stream>>>(
        xnb, Wint, xzb, W_out, Woutt, W_x, Wxt, W_dt, Wdtt,
        cond, film_gw, film_gb, film_bw, film_bb, gamma, beta);

    // conv+silu -> xproj -> dt, fused; 256 blocks x 8 waves, 16 tokens each
    mid_kernel<<<B_ * N_ / 16, 512, 0, stream>>>(
        xzb, conv_w, conv_b, Wxt, Wdtt, b_dt, ucb, xdbl, deltab);

    scan_p1<<<B_ * NC_ * 4, 256, 0, stream>>>(deltab, ucb, xdbl, A_log, hend, cumd);
    scan_comb<<<B_ * S_ * (E_ / 64), 256, 0, stream>>>(hend, cumd, A_log);
    scan_p3<<<B_ * NC_ * 4, 256, 0, stream>>>(deltab, ucb, xdbl, xzb, A_log, D_skip, hend, yb);

    // out = FiLM(y @ W_out)   [4096,1024]x[1024,512], 64x64 tiles, XCD-swizzled
    gemm2_kernel<64, 64>
        <<<512, 256, 0, stream>>>(
            yb, Woutt, out, B_ * N_, D_, E_, gamma, beta);
}